// Round 1
// baseline (1001.418 us; speedup 1.0000x reference)
//
#include <hip/hip_runtime.h>

#define NODES 13627
#define DIM   500
#define NEDGE 504378

// ---------------------------------------------------------------------------
// Wave (64-lane) butterfly reduction
// ---------------------------------------------------------------------------
__device__ inline float wave_reduce_sum(float v) {
#pragma unroll
    for (int o = 32; o > 0; o >>= 1) v += __shfl_xor(v, o, 64);
    return v;
}

// ---------------------------------------------------------------------------
// CSR build: histogram -> scan -> scatter
// ---------------------------------------------------------------------------
__global__ __launch_bounds__(256) void hist_kernel(const int* __restrict__ dst,
                                                   int* __restrict__ cnt, int E) {
    int i = blockIdx.x * blockDim.x + threadIdx.x;
    if (i < E) atomicAdd(&cnt[dst[i]], 1);
}

__global__ __launch_bounds__(1024) void scan_kernel(int* __restrict__ cnt_cur,
                                                    int* __restrict__ off, int n) {
    __shared__ int sd[1024];
    const int tid = threadIdx.x;
    int carry = 0;
    for (int base = 0; base < n; base += 1024) {
        int i = base + tid;
        int v = (i < n) ? cnt_cur[i] : 0;
        sd[tid] = v;
        __syncthreads();
#pragma unroll
        for (int o = 1; o < 1024; o <<= 1) {
            int t = (tid >= o) ? sd[tid - o] : 0;
            __syncthreads();
            sd[tid] += t;
            __syncthreads();
        }
        int excl = sd[tid] - v;          // exclusive prefix within chunk
        if (i < n) { off[i] = carry + excl; cnt_cur[i] = carry + excl; }
        int total = sd[1023];
        __syncthreads();                 // protect sd before next chunk
        carry += total;
    }
    if (tid == 0) off[n] = carry;
}

__global__ __launch_bounds__(256) void scatter_kernel(const int* __restrict__ src,
                                                      const int* __restrict__ dst,
                                                      int* __restrict__ cur,
                                                      int* __restrict__ ssrc, int E) {
    int i = blockIdx.x * blockDim.x + threadIdx.x;
    if (i < E) {
        int p = atomicAdd(&cur[dst[i]], 1);
        ssrc[p] = src[i];
    }
}

// ---------------------------------------------------------------------------
// fp32 tiled GEMM:  C = [ADD_BASE? base +] [RELU?relu]( A[M,K] @ W[K,Nn] [+bias] )
// 64x64 tile, BK=16, 256 threads, 4x4 micro-tile.
// ---------------------------------------------------------------------------
template <bool RELU, bool ADD_BASE, bool HAS_BIAS>
__global__ __launch_bounds__(256) void gemm_kernel(
    const float* __restrict__ A, const float* __restrict__ W,
    const float* __restrict__ bias, const float* __restrict__ base,
    float* __restrict__ C, int M, int K, int Nn) {
    __shared__ float As[16][68];  // [k][m], row stride 68 floats (16B aligned, bank-safe)
    __shared__ float Ws[16][68];  // [k][n]
    const int tid = threadIdx.x;
    const int tx = tid & 15, ty = tid >> 4;
    const int m0 = blockIdx.y * 64, n0 = blockIdx.x * 64;
    const int ar = tid >> 2;          // 0..63  (m within tile)
    const int ac = (tid & 3) << 2;    // 0,4,8,12 (k within tile)
    const int wr = tid >> 4;          // 0..15  (k within tile)
    const int wc = (tid & 15) << 2;   // 0..60  (n within tile)
    float acc[4][4] = {};

    for (int k0 = 0; k0 < K; k0 += 16) {
        {
            int m = m0 + ar;
            int kb = k0 + ac;
            if (m < M && kb + 3 < K) {
                const float4 v = *(const float4*)(A + (size_t)m * K + kb);
                As[ac + 0][ar] = v.x; As[ac + 1][ar] = v.y;
                As[ac + 2][ar] = v.z; As[ac + 3][ar] = v.w;
            } else {
#pragma unroll
                for (int j = 0; j < 4; j++) {
                    int k = kb + j;
                    As[ac + j][ar] = (m < M && k < K) ? A[(size_t)m * K + k] : 0.f;
                }
            }
            int k = k0 + wr;
            int nb = n0 + wc;
            if (k < K && nb + 3 < Nn) {
                const float4 v = *(const float4*)(W + (size_t)k * Nn + nb);
                Ws[wr][wc + 0] = v.x; Ws[wr][wc + 1] = v.y;
                Ws[wr][wc + 2] = v.z; Ws[wr][wc + 3] = v.w;
            } else {
#pragma unroll
                for (int j = 0; j < 4; j++) {
                    int n = nb + j;
                    Ws[wr][wc + j] = (k < K && n < Nn) ? W[(size_t)k * Nn + n] : 0.f;
                }
            }
        }
        __syncthreads();
#pragma unroll
        for (int kk = 0; kk < 16; kk++) {
            float a[4], w[4];
#pragma unroll
            for (int i = 0; i < 4; i++) a[i] = As[kk][ty * 4 + i];
#pragma unroll
            for (int j = 0; j < 4; j++) w[j] = Ws[kk][tx * 4 + j];
#pragma unroll
            for (int i = 0; i < 4; i++)
#pragma unroll
                for (int j = 0; j < 4; j++) acc[i][j] += a[i] * w[j];
        }
        __syncthreads();
    }

#pragma unroll
    for (int i = 0; i < 4; i++) {
        int m = m0 + ty * 4 + i;
        if (m >= M) continue;
#pragma unroll
        for (int j = 0; j < 4; j++) {
            int n = n0 + tx * 4 + j;
            if (n >= Nn) continue;
            float v = acc[i][j];
            if (HAS_BIAS) v += bias[n];
            if (RELU) v = fmaxf(v, 0.f);
            if (ADD_BASE) v += base[(size_t)m * Nn + n];
            C[(size_t)m * Nn + n] = v;
        }
    }
}

// ---------------------------------------------------------------------------
// GATv2 edge+aggregate, one wave per destination node, single-pass softmax.
// out[n,f] = relu?( sum_e a_e * xl[src_e,f] / sum_e a_e + bias[f] )
// Self-loop (src=n) handled implicitly as the first iteration.
// ---------------------------------------------------------------------------
template <int F, int FPL, bool RELU>
__global__ __launch_bounds__(256) void gat_node_kernel(
    const float* __restrict__ xl, const float* __restrict__ xr,
    const float* __restrict__ att, const float* __restrict__ bias,
    const int* __restrict__ off, const int* __restrict__ ssrc,
    float* __restrict__ out, int n) {
    const int wid = blockIdx.x * (blockDim.x >> 6) + (threadIdx.x >> 6);
    const int lane = threadIdx.x & 63;
    if (wid >= n) return;

    float attv[FPL], xrv[FPL], acc[FPL];
#pragma unroll
    for (int k = 0; k < FPL; k++) {
        int f = lane + 64 * k;
        bool ok = f < F;
        attv[k] = ok ? att[f] : 0.f;
        xrv[k]  = ok ? xr[(size_t)wid * F + f] : 0.f;
        acc[k] = 0.f;
    }
    float den = 0.f;
    const int s0 = off[wid], s1 = off[wid + 1];
    for (int e = s0 - 1; e < s1; e++) {
        int src = (e < s0) ? wid : ssrc[e];
        float xlv[FPL];
        float p = 0.f;
#pragma unroll
        for (int k = 0; k < FPL; k++) {
            int f = lane + 64 * k;
            xlv[k] = (f < F) ? xl[(size_t)src * F + f] : 0.f;
            float t = xlv[k] + xrv[k];
            float g = t > 0.f ? t : 0.2f * t;
            p += attv[k] * g;
        }
        p = wave_reduce_sum(p);   // all lanes hold score
        float ex = expf(p);
        den += ex;
#pragma unroll
        for (int k = 0; k < FPL; k++) acc[k] += ex * xlv[k];
    }
    float inv = 1.f / (den + 1e-16f);
#pragma unroll
    for (int k = 0; k < FPL; k++) {
        int f = lane + 64 * k;
        if (f < F) {
            float v = acc[k] * inv + bias[f];
            if (RELU) v = fmaxf(v, 0.f);
            out[(size_t)wid * F + f] = v;
        }
    }
}

// ---------------------------------------------------------------------------
// Layer-3 projections: xl3 = xo @ Wl3, xr3 = xo @ Wr3   (K=100, Nn=1)
// ---------------------------------------------------------------------------
__global__ __launch_bounds__(256) void gemm_vec1_kernel(
    const float* __restrict__ xo, const float* __restrict__ wl,
    const float* __restrict__ wr, float* __restrict__ xl3,
    float* __restrict__ xr3, int M, int K) {
    const int wid = blockIdx.x * 4 + (threadIdx.x >> 6);
    const int lane = threadIdx.x & 63;
    if (wid >= M) return;
    float a = 0.f, b = 0.f;
    for (int f = lane; f < K; f += 64) {
        float v = xo[(size_t)wid * K + f];
        a += v * wl[f];
        b += v * wr[f];
    }
    a = wave_reduce_sum(a);
    b = wave_reduce_sum(b);
    if (lane == 0) { xl3[wid] = a; xr3[wid] = b; }
}

// ---------------------------------------------------------------------------
// Layer-3 GAT (F=1): thread per node, writes final out[N] to d_out.
// ---------------------------------------------------------------------------
__global__ __launch_bounds__(256) void gat3_kernel(
    const float* __restrict__ xl3, const float* __restrict__ xr3,
    const float* __restrict__ att3, const float* __restrict__ b3,
    const int* __restrict__ off, const int* __restrict__ ssrc,
    float* __restrict__ out, int n) {
    int i = blockIdx.x * blockDim.x + threadIdx.x;
    if (i >= n) return;
    const float xrv = xr3[i];
    const float att = att3[0];
    float num = 0.f, den = 0.f;
    const int s0 = off[i], s1 = off[i + 1];
    for (int e = s0 - 1; e < s1; e++) {
        int src = (e < s0) ? i : ssrc[e];
        float xlv = xl3[src];
        float t = xlv + xrv;
        float g = t > 0.f ? t : 0.2f * t;
        float ex = expf(g * att);
        den += ex;
        num += ex * xlv;
    }
    out[i] = num / (den + 1e-16f) + b3[0];
}

// ---------------------------------------------------------------------------
// Link-prediction loss. One wave per edge item, grid-stride over 2E items.
// fp32 sigmoid saturation must match the fp32 numpy reference exactly.
// ---------------------------------------------------------------------------
__global__ __launch_bounds__(256) void loss_kernel(
    const float* __restrict__ z, const int* __restrict__ pos,
    const int* __restrict__ neg, float* __restrict__ lsum, int E) {
    const int lane = threadIdx.x & 63;
    const int wlocal = threadIdx.x >> 6;
    const int wid = blockIdx.x * 4 + wlocal;
    const int nw = gridDim.x * 4;
    float psum = 0.f, nsum = 0.f;
    for (int item = wid; item < 2 * E; item += nw) {
        bool isNeg = item >= E;
        int e = isNeg ? item - E : item;
        const int* ei = isNeg ? neg : pos;
        int u = ei[e], v = ei[E + e];
        const float* zu = z + (size_t)u * 100;
        const float* zv = z + (size_t)v * 100;
        float p = zu[lane] * zv[lane];
        if (lane < 36) p += zu[lane + 64] * zv[lane + 64];
        p = wave_reduce_sum(p);
        if (lane == 0) {
            float sig = 1.f / (1.f + expf(-p));
            if (isNeg) nsum += logf(1.f - sig + 1e-15f);
            else       psum += logf(sig + 1e-15f);
        }
    }
    __shared__ float sp[4], sn[4];
    if (lane == 0) { sp[wlocal] = psum; sn[wlocal] = nsum; }
    __syncthreads();
    if (threadIdx.x == 0) {
        atomicAdd(&lsum[0], sp[0] + sp[1] + sp[2] + sp[3]);
        atomicAdd(&lsum[1], sn[0] + sn[1] + sn[2] + sn[3]);
    }
}

__global__ void finalize_kernel(const float* __restrict__ lsum,
                                const float* __restrict__ c1,
                                const float* __restrict__ c2,
                                float* __restrict__ out, int n, int E) {
    out[n]     = -(lsum[0] + lsum[1]) / (float)E;
    out[n + 1] = c1[0];
    out[n + 2] = c2[0];
}

// ---------------------------------------------------------------------------
extern "C" void kernel_launch(void* const* d_in, const int* in_sizes, int n_in,
                              void* d_out, int out_size, void* d_ws, size_t ws_size,
                              hipStream_t stream) {
    const float* x      = (const float*)d_in[0];
    const int*   ei     = (const int*)d_in[1];   // [2,E]: src=ei, dst=ei+E
    const int*   nei    = (const int*)d_in[2];
    const float* Wl1    = (const float*)d_in[3];
    const float* Wr1    = (const float*)d_in[4];
    const float* att1   = (const float*)d_in[5];
    const float* b1     = (const float*)d_in[6];
    const float* Wl2    = (const float*)d_in[7];
    const float* Wr2    = (const float*)d_in[8];
    const float* att2   = (const float*)d_in[9];
    const float* b2     = (const float*)d_in[10];
    const float* Wl3    = (const float*)d_in[11];
    const float* Wr3    = (const float*)d_in[12];
    const float* att3   = (const float*)d_in[13];
    const float* b3     = (const float*)d_in[14];
    const float* Wlin1  = (const float*)d_in[15];
    const float* blin1  = (const float*)d_in[16];
    const float* Wlin2  = (const float*)d_in[17];
    const float* blin2  = (const float*)d_in[18];
    const float* c1     = (const float*)d_in[19];
    const float* c2     = (const float*)d_in[20];
    float* out = (float*)d_out;

    const int E = in_sizes[1] / 2;   // 504378
    const int N = NODES;

    // ---- workspace carve (~51.3 MB total; all offsets 4KB-ish aligned) ----
    const size_t SZ300 = 4088832;   // >= N*300
    const size_t SZ100 = 1363968;   // >= N*100
    float* fws = (float*)d_ws;
    float* xl1 = fws;
    float* xr1 = fws + SZ300;
    float* h1  = fws + 2 * SZ300;
    float* xl2 = xl1;                    // reuse A after layer-1
    float* xr2 = xl1 + SZ100;
    float* h2  = xr1;                    // reuse B
    float* xo  = h1;                     // reuse C after layer-2 gemms
    float* z   = h1 + SZ100;
    float* xl3 = xl1 + 2 * SZ100;
    float* xr3 = xl3 + 14336;
    int*   ioff = (int*)(fws + 3 * SZ300);   // N+1
    int*   cur  = ioff + (N + 1);            // N (counts, then cursors)
    int*   ssrc = cur + N;                   // E
    float* lsum = (float*)(ssrc + E);        // 2

    // ---- zero the bits that need it (ws is poisoned 0xAA every call) ----
    hipMemsetAsync(cur, 0, sizeof(int) * N, stream);
    hipMemsetAsync(lsum, 0, sizeof(float) * 2, stream);

    // ---- CSR build (group edges by dst; self-loops handled implicitly) ----
    hist_kernel<<<(E + 255) / 256, 256, 0, stream>>>(ei + E, cur, E);
    scan_kernel<<<1, 1024, 0, stream>>>(cur, ioff, N);
    scatter_kernel<<<(E + 255) / 256, 256, 0, stream>>>(ei, ei + E, cur, ssrc, E);

    // ---- layer 1 ----
    dim3 g300((300 + 63) / 64, (N + 63) / 64);   // (5, 213)
    dim3 g100((100 + 63) / 64, (N + 63) / 64);   // (2, 213)
    gemm_kernel<false, false, false><<<g300, 256, 0, stream>>>(x, Wl1, nullptr, nullptr, xl1, N, DIM, 300);
    gemm_kernel<false, false, false><<<g300, 256, 0, stream>>>(x, Wr1, nullptr, nullptr, xr1, N, DIM, 300);
    gat_node_kernel<300, 5, true><<<(N + 3) / 4, 256, 0, stream>>>(xl1, xr1, att1, b1, ioff, ssrc, h1, N);

    // ---- layer 2 ----
    gemm_kernel<false, false, false><<<g100, 256, 0, stream>>>(h1, Wl2, nullptr, nullptr, xl2, N, 300, 100);
    gemm_kernel<false, false, false><<<g100, 256, 0, stream>>>(h1, Wr2, nullptr, nullptr, xr2, N, 300, 100);
    gat_node_kernel<100, 2, true><<<(N + 3) / 4, 256, 0, stream>>>(xl2, xr2, att2, b2, ioff, ssrc, h2, N);

    // ---- skip connections ----
    gemm_kernel<true, true, true><<<g100, 256, 0, stream>>>(x, Wlin1, blin1, h2, xo, N, DIM, 100);
    gemm_kernel<true, true, true><<<g100, 256, 0, stream>>>(x, Wlin2, blin2, h2, z, N, DIM, 100);

    // ---- reconstruction loss ----
    loss_kernel<<<1024, 256, 0, stream>>>(z, ei, nei, lsum, E);

    // ---- layer 3 ----
    gemm_vec1_kernel<<<(N + 3) / 4, 256, 0, stream>>>(xo, Wl3, Wr3, xl3, xr3, N, 100);
    gat3_kernel<<<(N + 255) / 256, 256, 0, stream>>>(xl3, xr3, att3, b3, ioff, ssrc, out, N);

    finalize_kernel<<<1, 1, 0, stream>>>(lsum, c1, c2, out, N, E);
}

// Round 2
// 853.754 us; speedup vs baseline: 1.1730x; 1.1730x over previous
//
#include <hip/hip_runtime.h>

#define NODES 13627
#define DIM   500
#define NEDGE 504378

// ---------------------------------------------------------------------------
// Wave (64-lane) butterfly reduction
// ---------------------------------------------------------------------------
__device__ inline float wave_reduce_sum(float v) {
#pragma unroll
    for (int o = 32; o > 0; o >>= 1) v += __shfl_xor(v, o, 64);
    return v;
}

// ---------------------------------------------------------------------------
// CSR build: histogram -> scan -> scatter
// ---------------------------------------------------------------------------
__global__ __launch_bounds__(256) void hist_kernel(const int* __restrict__ dst,
                                                   int* __restrict__ cnt, int E) {
    int i = blockIdx.x * blockDim.x + threadIdx.x;
    if (i < E) atomicAdd(&cnt[dst[i]], 1);
}

__global__ __launch_bounds__(1024) void scan_kernel(int* __restrict__ cnt_cur,
                                                    int* __restrict__ off, int n) {
    __shared__ int sd[1024];
    const int tid = threadIdx.x;
    int carry = 0;
    for (int base = 0; base < n; base += 1024) {
        int i = base + tid;
        int v = (i < n) ? cnt_cur[i] : 0;
        sd[tid] = v;
        __syncthreads();
#pragma unroll
        for (int o = 1; o < 1024; o <<= 1) {
            int t = (tid >= o) ? sd[tid - o] : 0;
            __syncthreads();
            sd[tid] += t;
            __syncthreads();
        }
        int excl = sd[tid] - v;          // exclusive prefix within chunk
        if (i < n) { off[i] = carry + excl; cnt_cur[i] = carry + excl; }
        int total = sd[1023];
        __syncthreads();                 // protect sd before next chunk
        carry += total;
    }
    if (tid == 0) off[n] = carry;
}

__global__ __launch_bounds__(256) void scatter_kernel(const int* __restrict__ src,
                                                      const int* __restrict__ dst,
                                                      int* __restrict__ cur,
                                                      int* __restrict__ ssrc, int E) {
    int i = blockIdx.x * blockDim.x + threadIdx.x;
    if (i < E) {
        int p = atomicAdd(&cur[dst[i]], 1);
        ssrc[p] = src[i];
    }
}

// ---------------------------------------------------------------------------
// fp32 tiled GEMM:  C = [ADD_BASE? base +] [RELU?relu]( A[M,K] @ W[K,Nn] [+bias] )
// 64x64 tile, BK=16, 256 threads, 4x4 micro-tile.
// ---------------------------------------------------------------------------
template <bool RELU, bool ADD_BASE, bool HAS_BIAS>
__global__ __launch_bounds__(256) void gemm_kernel(
    const float* __restrict__ A, const float* __restrict__ W,
    const float* __restrict__ bias, const float* __restrict__ base,
    float* __restrict__ C, int M, int K, int Nn) {
    __shared__ float As[16][68];  // [k][m]
    __shared__ float Ws[16][68];  // [k][n]
    const int tid = threadIdx.x;
    const int tx = tid & 15, ty = tid >> 4;
    const int m0 = blockIdx.y * 64, n0 = blockIdx.x * 64;
    const int ar = tid >> 2;          // 0..63  (m within tile)
    const int ac = (tid & 3) << 2;    // 0,4,8,12 (k within tile)
    const int wr = tid >> 4;          // 0..15  (k within tile)
    const int wc = (tid & 15) << 2;   // 0..60  (n within tile)
    float acc[4][4] = {};

    for (int k0 = 0; k0 < K; k0 += 16) {
        {
            int m = m0 + ar;
            int kb = k0 + ac;
            if (m < M && kb + 3 < K) {
                const float4 v = *(const float4*)(A + (size_t)m * K + kb);
                As[ac + 0][ar] = v.x; As[ac + 1][ar] = v.y;
                As[ac + 2][ar] = v.z; As[ac + 3][ar] = v.w;
            } else {
#pragma unroll
                for (int j = 0; j < 4; j++) {
                    int k = kb + j;
                    As[ac + j][ar] = (m < M && k < K) ? A[(size_t)m * K + k] : 0.f;
                }
            }
            int k = k0 + wr;
            int nb = n0 + wc;
            if (k < K && nb + 3 < Nn) {
                const float4 v = *(const float4*)(W + (size_t)k * Nn + nb);
                Ws[wr][wc + 0] = v.x; Ws[wr][wc + 1] = v.y;
                Ws[wr][wc + 2] = v.z; Ws[wr][wc + 3] = v.w;
            } else {
#pragma unroll
                for (int j = 0; j < 4; j++) {
                    int n = nb + j;
                    Ws[wr][wc + j] = (k < K && n < Nn) ? W[(size_t)k * Nn + n] : 0.f;
                }
            }
        }
        __syncthreads();
#pragma unroll
        for (int kk = 0; kk < 16; kk++) {
            float a[4], w[4];
#pragma unroll
            for (int i = 0; i < 4; i++) a[i] = As[kk][ty * 4 + i];
#pragma unroll
            for (int j = 0; j < 4; j++) w[j] = Ws[kk][tx * 4 + j];
#pragma unroll
            for (int i = 0; i < 4; i++)
#pragma unroll
                for (int j = 0; j < 4; j++) acc[i][j] += a[i] * w[j];
        }
        __syncthreads();
    }

#pragma unroll
    for (int i = 0; i < 4; i++) {
        int m = m0 + ty * 4 + i;
        if (m >= M) continue;
#pragma unroll
        for (int j = 0; j < 4; j++) {
            int n = n0 + tx * 4 + j;
            if (n >= Nn) continue;
            float v = acc[i][j];
            if (HAS_BIAS) v += bias[n];
            if (RELU) v = fmaxf(v, 0.f);
            if (ADD_BASE) v += base[(size_t)m * Nn + n];
            C[(size_t)m * Nn + n] = v;
        }
    }
}

// ---------------------------------------------------------------------------
// GATv2 edge+aggregate, one wave per destination node, single-pass softmax.
// ---------------------------------------------------------------------------
template <int F, int FPL, bool RELU>
__global__ __launch_bounds__(256) void gat_node_kernel(
    const float* __restrict__ xl, const float* __restrict__ xr,
    const float* __restrict__ att, const float* __restrict__ bias,
    const int* __restrict__ off, const int* __restrict__ ssrc,
    float* __restrict__ out, int n) {
    const int wid = blockIdx.x * (blockDim.x >> 6) + (threadIdx.x >> 6);
    const int lane = threadIdx.x & 63;
    if (wid >= n) return;

    float attv[FPL], xrv[FPL], acc[FPL];
#pragma unroll
    for (int k = 0; k < FPL; k++) {
        int f = lane + 64 * k;
        bool ok = f < F;
        attv[k] = ok ? att[f] : 0.f;
        xrv[k]  = ok ? xr[(size_t)wid * F + f] : 0.f;
        acc[k] = 0.f;
    }
    float den = 0.f;
    const int s0 = off[wid], s1 = off[wid + 1];
    for (int e = s0 - 1; e < s1; e++) {
        int src = (e < s0) ? wid : ssrc[e];
        float xlv[FPL];
        float p = 0.f;
#pragma unroll
        for (int k = 0; k < FPL; k++) {
            int f = lane + 64 * k;
            xlv[k] = (f < F) ? xl[(size_t)src * F + f] : 0.f;
            float t = xlv[k] + xrv[k];
            float g = t > 0.f ? t : 0.2f * t;
            p += attv[k] * g;
        }
        p = wave_reduce_sum(p);   // all lanes hold score
        float ex = expf(p);
        den += ex;
#pragma unroll
        for (int k = 0; k < FPL; k++) acc[k] += ex * xlv[k];
    }
    float inv = 1.f / (den + 1e-16f);
#pragma unroll
    for (int k = 0; k < FPL; k++) {
        int f = lane + 64 * k;
        if (f < F) {
            float v = acc[k] * inv + bias[f];
            if (RELU) v = fmaxf(v, 0.f);
            out[(size_t)wid * F + f] = v;
        }
    }
}

// ---------------------------------------------------------------------------
// Layer-3 projections: xl3 = xo @ Wl3, xr3 = xo @ Wr3   (K=100, Nn=1)
// ---------------------------------------------------------------------------
__global__ __launch_bounds__(256) void gemm_vec1_kernel(
    const float* __restrict__ xo, const float* __restrict__ wl,
    const float* __restrict__ wr, float* __restrict__ xl3,
    float* __restrict__ xr3, int M, int K) {
    const int wid = blockIdx.x * 4 + (threadIdx.x >> 6);
    const int lane = threadIdx.x & 63;
    if (wid >= M) return;
    float a = 0.f, b = 0.f;
    for (int f = lane; f < K; f += 64) {
        float v = xo[(size_t)wid * K + f];
        a += v * wl[f];
        b += v * wr[f];
    }
    a = wave_reduce_sum(a);
    b = wave_reduce_sum(b);
    if (lane == 0) { xl3[wid] = a; xr3[wid] = b; }
}

// ---------------------------------------------------------------------------
// Layer-3 GAT (F=1): thread per node, writes final out[N] to d_out.
// ---------------------------------------------------------------------------
__global__ __launch_bounds__(256) void gat3_kernel(
    const float* __restrict__ xl3, const float* __restrict__ xr3,
    const float* __restrict__ att3, const float* __restrict__ b3,
    const int* __restrict__ off, const int* __restrict__ ssrc,
    float* __restrict__ out, int n) {
    int i = blockIdx.x * blockDim.x + threadIdx.x;
    if (i >= n) return;
    const float xrv = xr3[i];
    const float att = att3[0];
    float num = 0.f, den = 0.f;
    const int s0 = off[i], s1 = off[i + 1];
    for (int e = s0 - 1; e < s1; e++) {
        int src = (e < s0) ? i : ssrc[e];
        float xlv = xl3[src];
        float t = xlv + xrv;
        float g = t > 0.f ? t : 0.2f * t;
        float ex = expf(g * att);
        den += ex;
        num += ex * xlv;
    }
    out[i] = num / (den + 1e-16f) + b3[0];
}

// ---------------------------------------------------------------------------
// Link-prediction loss. 4-way item-interleaved, grid-stride over 2E items.
// All 16 gather loads for 4 items issued before any reduction (MLP).
// ---------------------------------------------------------------------------
__global__ __launch_bounds__(256) void loss_kernel(
    const float* __restrict__ z, const int* __restrict__ pos,
    const int* __restrict__ neg, float* __restrict__ lsum, int E) {
    const int lane = threadIdx.x & 63;
    const int wlocal = threadIdx.x >> 6;
    const int wid = blockIdx.x * 4 + wlocal;
    const int nw = gridDim.x * 4;
    const int total = 2 * E;
    float psum = 0.f, nsum = 0.f;

    for (int base = wid; base < total; base += 4 * nw) {
        int   it[4];
        bool  act[4], isNeg[4];
        const float *zu[4], *zv[4];
#pragma unroll
        for (int q = 0; q < 4; q++) {
            it[q] = base + q * nw;
            act[q] = it[q] < total;
            int itc = act[q] ? it[q] : 0;
            isNeg[q] = itc >= E;
            int e = isNeg[q] ? itc - E : itc;
            const int* ei = isNeg[q] ? neg : pos;
            int u = ei[e], v = ei[E + e];
            zu[q] = z + (size_t)u * 100;
            zv[q] = z + (size_t)v * 100;
        }
        // issue all gathers up front
        float a0[4], a1[4], b0[4], b1[4];
#pragma unroll
        for (int q = 0; q < 4; q++) {
            a0[q] = zu[q][lane];
            b0[q] = zv[q][lane];
            a1[q] = (lane < 36) ? zu[q][lane + 64] : 0.f;
            b1[q] = (lane < 36) ? zv[q][lane + 64] : 0.f;
        }
#pragma unroll
        for (int q = 0; q < 4; q++) {
            float p = a0[q] * b0[q] + a1[q] * b1[q];
            p = wave_reduce_sum(p);
            if (lane == 0 && act[q]) {
                float sig = 1.f / (1.f + expf(-p));
                if (isNeg[q]) nsum += logf(1.f - sig + 1e-15f);
                else          psum += logf(sig + 1e-15f);
            }
        }
    }
    __shared__ float sp[4], sn[4];
    if (lane == 0) { sp[wlocal] = psum; sn[wlocal] = nsum; }
    __syncthreads();
    if (threadIdx.x == 0) {
        atomicAdd(&lsum[0], sp[0] + sp[1] + sp[2] + sp[3]);
        atomicAdd(&lsum[1], sn[0] + sn[1] + sn[2] + sn[3]);
    }
}

__global__ void finalize_kernel(const float* __restrict__ lsum,
                                const float* __restrict__ c1,
                                const float* __restrict__ c2,
                                float* __restrict__ out, int n, int E) {
    out[n]     = -(lsum[0] + lsum[1]) / (float)E;
    out[n + 1] = c1[0];
    out[n + 2] = c2[0];
}

// ---------------------------------------------------------------------------
extern "C" void kernel_launch(void* const* d_in, const int* in_sizes, int n_in,
                              void* d_out, int out_size, void* d_ws, size_t ws_size,
                              hipStream_t stream) {
    const float* x      = (const float*)d_in[0];
    const int*   ei     = (const int*)d_in[1];   // [2,E]: src=ei, dst=ei+E
    const int*   nei    = (const int*)d_in[2];
    const float* Wl1    = (const float*)d_in[3];
    const float* Wr1    = (const float*)d_in[4];
    const float* att1   = (const float*)d_in[5];
    const float* b1     = (const float*)d_in[6];
    const float* Wl2    = (const float*)d_in[7];
    const float* Wr2    = (const float*)d_in[8];
    const float* att2   = (const float*)d_in[9];
    const float* b2     = (const float*)d_in[10];
    const float* Wl3    = (const float*)d_in[11];
    const float* Wr3    = (const float*)d_in[12];
    const float* att3   = (const float*)d_in[13];
    const float* b3     = (const float*)d_in[14];
    const float* Wlin1  = (const float*)d_in[15];
    const float* blin1  = (const float*)d_in[16];
    const float* Wlin2  = (const float*)d_in[17];
    const float* blin2  = (const float*)d_in[18];
    const float* c1     = (const float*)d_in[19];
    const float* c2     = (const float*)d_in[20];
    float* out = (float*)d_out;

    const int E = in_sizes[1] / 2;   // 504378
    const int N = NODES;

    // ---- workspace carve ----
    const size_t SZ300 = 4088832;   // >= N*300
    const size_t SZ100 = 1363968;   // >= N*100
    float* fws = (float*)d_ws;
    float* xl1 = fws;
    float* xr1 = fws + SZ300;
    float* h1  = fws + 2 * SZ300;
    float* xl2 = xl1;                    // reuse A after layer-1
    float* xr2 = xl1 + SZ100;
    float* h2  = xr1;                    // reuse B
    float* xo  = h1;                     // reuse C after layer-2 gemms
    float* z   = h1 + SZ100;
    float* xl3 = xl1 + 2 * SZ100;
    float* xr3 = xl3 + 14336;
    int*   ioff = (int*)(fws + 3 * SZ300);   // N+1
    int*   cur  = ioff + (N + 1);            // N (counts, then cursors)
    int*   ssrc = cur + N;                   // E
    float* lsum = (float*)(ssrc + E);        // 2

    hipMemsetAsync(cur, 0, sizeof(int) * N, stream);
    hipMemsetAsync(lsum, 0, sizeof(float) * 2, stream);

    // ---- CSR build ----
    hist_kernel<<<(E + 255) / 256, 256, 0, stream>>>(ei + E, cur, E);
    scan_kernel<<<1, 1024, 0, stream>>>(cur, ioff, N);
    scatter_kernel<<<(E + 255) / 256, 256, 0, stream>>>(ei, ei + E, cur, ssrc, E);

    // ---- layer 1 ----
    dim3 g300((300 + 63) / 64, (N + 63) / 64);
    dim3 g100((100 + 63) / 64, (N + 63) / 64);
    gemm_kernel<false, false, false><<<g300, 256, 0, stream>>>(x, Wl1, nullptr, nullptr, xl1, N, DIM, 300);
    gemm_kernel<false, false, false><<<g300, 256, 0, stream>>>(x, Wr1, nullptr, nullptr, xr1, N, DIM, 300);
    gat_node_kernel<300, 5, true><<<(N + 3) / 4, 256, 0, stream>>>(xl1, xr1, att1, b1, ioff, ssrc, h1, N);

    // ---- layer 2 ----
    gemm_kernel<false, false, false><<<g100, 256, 0, stream>>>(h1, Wl2, nullptr, nullptr, xl2, N, 300, 100);
    gemm_kernel<false, false, false><<<g100, 256, 0, stream>>>(h1, Wr2, nullptr, nullptr, xr2, N, 300, 100);
    gat_node_kernel<100, 2, true><<<(N + 3) / 4, 256, 0, stream>>>(xl2, xr2, att2, b2, ioff, ssrc, h2, N);

    // ---- skip connections ----
    gemm_kernel<true, true, true><<<g100, 256, 0, stream>>>(x, Wlin1, blin1, h2, xo, N, DIM, 100);
    gemm_kernel<true, true, true><<<g100, 256, 0, stream>>>(x, Wlin2, blin2, h2, z, N, DIM, 100);

    // ---- reconstruction loss (4096 blocks: fill all 8192 wave slots) ----
    loss_kernel<<<4096, 256, 0, stream>>>(z, ei, nei, lsum, E);

    // ---- layer 3 ----
    gemm_vec1_kernel<<<(N + 3) / 4, 256, 0, stream>>>(xo, Wl3, Wr3, xl3, xr3, N, 100);
    gat3_kernel<<<(N + 255) / 256, 256, 0, stream>>>(xl3, xr3, att3, b3, ioff, ssrc, out, N);

    finalize_kernel<<<1, 1, 0, stream>>>(lsum, c1, c2, out, N, E);
}

// Round 3
// 571.785 us; speedup vs baseline: 1.7514x; 1.4931x over previous
//
#include <hip/hip_runtime.h>
#include <hip/hip_bf16.h>

#define NODES 13627
#define DIM   500

typedef short short8 __attribute__((ext_vector_type(8)));
typedef float f32x4 __attribute__((ext_vector_type(4)));

__device__ inline float wave_reduce_sum(float v) {
#pragma unroll
    for (int o = 32; o > 0; o >>= 1) v += __shfl_xor(v, o, 64);
    return v;
}

__device__ inline float tof(float v) { return v; }
__device__ inline float tof(__hip_bfloat16 v) { return __bfloat162float(v); }
__device__ inline void store_v(float* p, float v) { *p = v; }
__device__ inline void store_v(__hip_bfloat16* p, float v) { *p = __float2bfloat16(v); }

// ---------------------------------------------------------------------------
// CSR build: histogram -> scan -> scatter
// ---------------------------------------------------------------------------
__global__ __launch_bounds__(256) void hist_kernel(const int* __restrict__ dst,
                                                   int* __restrict__ cnt, int E) {
    int i = blockIdx.x * blockDim.x + threadIdx.x;
    if (i < E) atomicAdd(&cnt[dst[i]], 1);
}

__global__ __launch_bounds__(1024) void scan_kernel(int* __restrict__ cnt_cur,
                                                    int* __restrict__ off, int n) {
    __shared__ int sd[1024];
    const int tid = threadIdx.x;
    int carry = 0;
    for (int base = 0; base < n; base += 1024) {
        int i = base + tid;
        int v = (i < n) ? cnt_cur[i] : 0;
        sd[tid] = v;
        __syncthreads();
#pragma unroll
        for (int o = 1; o < 1024; o <<= 1) {
            int t = (tid >= o) ? sd[tid - o] : 0;
            __syncthreads();
            sd[tid] += t;
            __syncthreads();
        }
        int excl = sd[tid] - v;
        if (i < n) { off[i] = carry + excl; cnt_cur[i] = carry + excl; }
        int total = sd[1023];
        __syncthreads();
        carry += total;
    }
    if (tid == 0) off[n] = carry;
}

__global__ __launch_bounds__(256) void scatter_kernel(const int* __restrict__ src,
                                                      const int* __restrict__ dst,
                                                      int* __restrict__ cur,
                                                      int* __restrict__ ssrc, int E) {
    int i = blockIdx.x * blockDim.x + threadIdx.x;
    if (i < E) {
        int p = atomicAdd(&cur[dst[i]], 1);
        ssrc[p] = src[i];
    }
}

// ---------------------------------------------------------------------------
// Conversion / packing kernels (fp32 -> padded bf16, weights transposed+fused)
// ---------------------------------------------------------------------------
__global__ __launch_bounds__(256) void convert_x_kernel(const float* __restrict__ x,
                                                        __hip_bfloat16* __restrict__ xb, int M) {
    int i = blockIdx.x * 256 + threadIdx.x;
    if (i >= M * 512) return;
    int m = i >> 9, k = i & 511;
    xb[i] = __float2bfloat16(k < 500 ? x[m * 500 + k] : 0.f);
}

// W1T[n][k] (640x512): n<300 -> Wl1[k][n], n<600 -> Wr1[k][n-300]
__global__ __launch_bounds__(256) void convert_w1_kernel(const float* __restrict__ Wl,
                                                         const float* __restrict__ Wr,
                                                         __hip_bfloat16* __restrict__ WT) {
    int i = blockIdx.x * 256 + threadIdx.x;
    if (i >= 640 * 512) return;
    int n = i >> 9, k = i & 511;
    float v = 0.f;
    if (k < 500) {
        if (n < 300) v = Wl[k * 300 + n];
        else if (n < 600) v = Wr[k * 300 + n - 300];
    }
    WT[i] = __float2bfloat16(v);
}

// W2T[n][k] (256x320): n<100 -> Wl2[k][n], n<200 -> Wr2[k][n-100]
__global__ __launch_bounds__(256) void convert_w2_kernel(const float* __restrict__ Wl,
                                                         const float* __restrict__ Wr,
                                                         __hip_bfloat16* __restrict__ WT) {
    int i = blockIdx.x * 256 + threadIdx.x;
    if (i >= 256 * 320) return;
    int n = i / 320, k = i - n * 320;
    float v = 0.f;
    if (k < 300) {
        if (n < 100) v = Wl[k * 100 + n];
        else if (n < 200) v = Wr[k * 100 + n - 100];
    }
    WT[i] = __float2bfloat16(v);
}

// WsT[n][k] (256x512): n<100 -> Wlin1[k][n], n<200 -> Wlin2[k][n-100]
__global__ __launch_bounds__(256) void convert_ws_kernel(const float* __restrict__ W1,
                                                         const float* __restrict__ W2,
                                                         __hip_bfloat16* __restrict__ WT) {
    int i = blockIdx.x * 256 + threadIdx.x;
    if (i >= 256 * 512) return;
    int n = i >> 9, k = i & 511;
    float v = 0.f;
    if (k < 500) {
        if (n < 100) v = W1[k * 100 + n];
        else if (n < 200) v = W2[k * 100 + n - 100];
    }
    WT[i] = __float2bfloat16(v);
}

__global__ __launch_bounds__(256) void convert_bcat_kernel(const float* __restrict__ b1,
                                                           const float* __restrict__ b2,
                                                           float* __restrict__ bcat) {
    int n = threadIdx.x;
    float v = 0.f;
    if (n < 100) v = b1[n];
    else if (n < 200) v = b2[n - 100];
    bcat[n] = v;
}

// ---------------------------------------------------------------------------
// bf16 MFMA GEMM: C[M,Nn] = A[M,Kp] @ BT[Nn,Kp]^T
// BM=128, BN=64, BK=32; 256 threads = 4 waves, wave w -> rows [w*32, w*32+32).
// LDS holds tiles in exact MFMA fragment order -> conflict-free b128 reads.
// SKIP epilogue: C = relu(acc + bias[n]) + h2[m][n%100]  (only n<200 stored)
// ---------------------------------------------------------------------------
template <typename TC, bool SKIP>
__global__ __launch_bounds__(256) void mfma_gemm(
    const __hip_bfloat16* __restrict__ A, const __hip_bfloat16* __restrict__ BT,
    TC* __restrict__ C, const float* __restrict__ bias, const float* __restrict__ h2,
    int M, int Kp, int Nn, int ldc) {
    __shared__ short AsF[8 * 64 * 8];   // 8 m-tiles x 64 lanes x 8 elems
    __shared__ short BsF[4 * 64 * 8];   // 4 n-tiles x 64 lanes x 8 elems
    const int t = threadIdx.x;
    const int w = t >> 6, lane = t & 63;
    const int c = t & 3, rr = t >> 2;   // staging: 4 threads/row, rr=0..63
    const int m0 = blockIdx.y * 128, n0 = blockIdx.x * 64;

    f32x4 acc[2][4];
#pragma unroll
    for (int i = 0; i < 2; i++)
#pragma unroll
        for (int j = 0; j < 4; j++) acc[i][j] = (f32x4){0.f, 0.f, 0.f, 0.f};

    for (int k0 = 0; k0 < Kp; k0 += 32) {
#pragma unroll
        for (int r = 0; r < 2; r++) {       // A: 128 rows, 2 rounds
            int m = r * 64 + rr;
            int gm = m0 + m; if (gm >= M) gm = M - 1;
            float4 v = *(const float4*)(A + (size_t)gm * Kp + k0 + c * 8);
            int mi = m >> 4, sl = m & 15;
            *(float4*)(&AsF[(mi * 64 + c * 16 + sl) * 8]) = v;
        }
        {                                   // B: 64 rows, 1 round
            int n = rr;
            float4 v = *(const float4*)(BT + (size_t)(n0 + n) * Kp + k0 + c * 8);
            int ni = n >> 4, sl = n & 15;
            *(float4*)(&BsF[(ni * 64 + c * 16 + sl) * 8]) = v;
        }
        __syncthreads();
        short8 a0 = *(const short8*)(&AsF[((w * 2 + 0) * 64 + lane) * 8]);
        short8 a1 = *(const short8*)(&AsF[((w * 2 + 1) * 64 + lane) * 8]);
#pragma unroll
        for (int j = 0; j < 4; j++) {
            short8 b = *(const short8*)(&BsF[(j * 64 + lane) * 8]);
            acc[0][j] = __builtin_amdgcn_mfma_f32_16x16x32_bf16(a0, b, acc[0][j], 0, 0, 0);
            acc[1][j] = __builtin_amdgcn_mfma_f32_16x16x32_bf16(a1, b, acc[1][j], 0, 0, 0);
        }
        __syncthreads();
    }

    const int q = lane >> 4, sl = lane & 15;
#pragma unroll
    for (int i = 0; i < 2; i++) {
#pragma unroll
        for (int j = 0; j < 4; j++) {
#pragma unroll
            for (int reg = 0; reg < 4; reg++) {
                int gm = m0 + w * 32 + i * 16 + q * 4 + reg;
                int gn = n0 + j * 16 + sl;
                if (gm >= M) continue;
                float v = acc[i][j][reg];
                if constexpr (SKIP) {
                    if (gn < 200) {
                        int cn = gn < 100 ? gn : gn - 100;
                        v = fmaxf(v + bias[gn], 0.f) + h2[(size_t)gm * 100 + cn];
                        store_v(&C[(size_t)gm * ldc + gn], v);
                    }
                } else {
                    store_v(&C[(size_t)gm * ldc + gn], v);
                }
            }
        }
    }
}

// ---------------------------------------------------------------------------
// GATv2 edge+aggregate, one wave per dst node, single-pass softmax.
// xl row = xl + src*SIN ; xr row = xr + wid*SIN (pointers pre-offset).
// Writes SOUT cols (zero-pads [F, SOUT) for downstream padded GEMM).
// ---------------------------------------------------------------------------
template <int F, int FPL, int SIN, int SOUT, typename TIN, typename TOUT, bool RELU>
__global__ __launch_bounds__(256) void gat_node_kernel(
    const TIN* __restrict__ xl, const TIN* __restrict__ xr,
    const float* __restrict__ att, const float* __restrict__ bias,
    const int* __restrict__ off, const int* __restrict__ ssrc,
    TOUT* __restrict__ out, int n) {
    const int wid = blockIdx.x * 4 + (threadIdx.x >> 6);
    const int lane = threadIdx.x & 63;
    if (wid >= n) return;

    float attv[FPL], xrv[FPL], acc[FPL];
#pragma unroll
    for (int k = 0; k < FPL; k++) {
        int f = lane + 64 * k;
        bool ok = f < F;
        attv[k] = ok ? att[f] : 0.f;
        xrv[k]  = ok ? tof(xr[(size_t)wid * SIN + f]) : 0.f;
        acc[k] = 0.f;
    }
    float den = 0.f;
    const int s0 = off[wid], s1 = off[wid + 1];
    for (int e = s0 - 1; e < s1; e++) {
        int src = (e < s0) ? wid : ssrc[e];
        float xlv[FPL];
        float p = 0.f;
#pragma unroll
        for (int k = 0; k < FPL; k++) {
            int f = lane + 64 * k;
            xlv[k] = (f < F) ? tof(xl[(size_t)src * SIN + f]) : 0.f;
            float tt = xlv[k] + xrv[k];
            float g = tt > 0.f ? tt : 0.2f * tt;
            p += attv[k] * g;
        }
        p = wave_reduce_sum(p);
        float ex = expf(p);
        den += ex;
#pragma unroll
        for (int k = 0; k < FPL; k++) acc[k] += ex * xlv[k];
    }
    float inv = 1.f / (den + 1e-16f);
#pragma unroll
    for (int k = 0; k < FPL; k++) {
        int f = lane + 64 * k;
        if (f < SOUT) {
            float v = 0.f;
            if (f < F) {
                v = acc[k] * inv + bias[f];
                if (RELU) v = fmaxf(v, 0.f);
            }
            store_v(&out[(size_t)wid * SOUT + f], v);
        }
    }
}

// ---------------------------------------------------------------------------
// Layer-3 projections: xl3 = xo @ Wl3, xr3 = xo @ Wr3  (K=100, xo stride ldx)
// ---------------------------------------------------------------------------
__global__ __launch_bounds__(256) void gemm_vec1_kernel(
    const float* __restrict__ xo, const float* __restrict__ wl,
    const float* __restrict__ wr, float* __restrict__ xl3,
    float* __restrict__ xr3, int M, int ldx) {
    const int wid = blockIdx.x * 4 + (threadIdx.x >> 6);
    const int lane = threadIdx.x & 63;
    if (wid >= M) return;
    float a = 0.f, b = 0.f;
    for (int f = lane; f < 100; f += 64) {
        float v = xo[(size_t)wid * ldx + f];
        a += v * wl[f];
        b += v * wr[f];
    }
    a = wave_reduce_sum(a);
    b = wave_reduce_sum(b);
    if (lane == 0) { xl3[wid] = a; xr3[wid] = b; }
}

__global__ __launch_bounds__(256) void gat3_kernel(
    const float* __restrict__ xl3, const float* __restrict__ xr3,
    const float* __restrict__ att3, const float* __restrict__ b3,
    const int* __restrict__ off, const int* __restrict__ ssrc,
    float* __restrict__ out, int n) {
    int i = blockIdx.x * blockDim.x + threadIdx.x;
    if (i >= n) return;
    const float xrv = xr3[i];
    const float att = att3[0];
    float num = 0.f, den = 0.f;
    const int s0 = off[i], s1 = off[i + 1];
    for (int e = s0 - 1; e < s1; e++) {
        int src = (e < s0) ? i : ssrc[e];
        float xlv = xl3[src];
        float t = xlv + xrv;
        float g = t > 0.f ? t : 0.2f * t;
        float ex = expf(g * att);
        den += ex;
        num += ex * xlv;
    }
    out[i] = num / (den + 1e-16f) + b3[0];
}

// ---------------------------------------------------------------------------
// Link-prediction loss: 16 lanes per item (4 items/wave, one per quad),
// float4 row loads, 4-step intra-quad reduce, 2-way item interleave.
// ---------------------------------------------------------------------------
__global__ __launch_bounds__(256) void loss_kernel(
    const float* __restrict__ z, const int* __restrict__ pos,
    const int* __restrict__ neg, float* __restrict__ lsum, int E, int ldz) {
    const int lane = threadIdx.x & 63;
    const int sl = lane & 15;
    const int q = lane >> 4;
    const int wlocal = threadIdx.x >> 6;
    const int nq = gridDim.x * 16;                     // total quads
    const int qid = (blockIdx.x * 4 + wlocal) * 4 + q;
    const int total = 2 * E;
    float psum = 0.f, nsum = 0.f;
    const float4 zero4 = {0.f, 0.f, 0.f, 0.f};

    for (int base = qid; base < total; base += 2 * nq) {
        float4 a0[2], a1[2], b0[2], b1[2];
        bool act[2], isN[2];
#pragma unroll
        for (int s = 0; s < 2; s++) {
            int it = base + s * nq;
            act[s] = it < total;
            int itc = act[s] ? it : 0;
            isN[s] = itc >= E;
            int e = isN[s] ? itc - E : itc;
            const int* ei = isN[s] ? neg : pos;
            int u = ei[e], v = ei[E + e];
            const float* zu = z + (size_t)u * ldz;
            const float* zv = z + (size_t)v * ldz;
            a0[s] = *(const float4*)(zu + sl * 4);
            b0[s] = *(const float4*)(zv + sl * 4);
            a1[s] = (sl < 9) ? *(const float4*)(zu + 64 + sl * 4) : zero4;
            b1[s] = (sl < 9) ? *(const float4*)(zv + 64 + sl * 4) : zero4;
        }
#pragma unroll
        for (int s = 0; s < 2; s++) {
            float p = a0[s].x * b0[s].x + a0[s].y * b0[s].y + a0[s].z * b0[s].z + a0[s].w * b0[s].w
                    + a1[s].x * b1[s].x + a1[s].y * b1[s].y + a1[s].z * b1[s].z + a1[s].w * b1[s].w;
            p += __shfl_xor(p, 1, 64);
            p += __shfl_xor(p, 2, 64);
            p += __shfl_xor(p, 4, 64);
            p += __shfl_xor(p, 8, 64);
            if (sl == 0 && act[s]) {
                float sig = 1.f / (1.f + expf(-p));
                if (isN[s]) nsum += logf(1.f - sig + 1e-15f);
                else        psum += logf(sig + 1e-15f);
            }
        }
    }
    float pw = wave_reduce_sum(psum);   // non-leader lanes hold 0
    float nw = wave_reduce_sum(nsum);
    __shared__ float sp[4], sn[4];
    if (lane == 0) { sp[wlocal] = pw; sn[wlocal] = nw; }
    __syncthreads();
    if (threadIdx.x == 0) {
        atomicAdd(&lsum[0], sp[0] + sp[1] + sp[2] + sp[3]);
        atomicAdd(&lsum[1], sn[0] + sn[1] + sn[2] + sn[3]);
    }
}

__global__ void finalize_kernel(const float* __restrict__ lsum,
                                const float* __restrict__ c1,
                                const float* __restrict__ c2,
                                float* __restrict__ out, int n, int E) {
    out[n]     = -(lsum[0] + lsum[1]) / (float)E;
    out[n + 1] = c1[0];
    out[n + 2] = c2[0];
}

// ---------------------------------------------------------------------------
extern "C" void kernel_launch(void* const* d_in, const int* in_sizes, int n_in,
                              void* d_out, int out_size, void* d_ws, size_t ws_size,
                              hipStream_t stream) {
    const float* x      = (const float*)d_in[0];
    const int*   ei     = (const int*)d_in[1];
    const int*   nei    = (const int*)d_in[2];
    const float* Wl1    = (const float*)d_in[3];
    const float* Wr1    = (const float*)d_in[4];
    const float* att1   = (const float*)d_in[5];
    const float* b1     = (const float*)d_in[6];
    const float* Wl2    = (const float*)d_in[7];
    const float* Wr2    = (const float*)d_in[8];
    const float* att2   = (const float*)d_in[9];
    const float* b2     = (const float*)d_in[10];
    const float* Wl3    = (const float*)d_in[11];
    const float* Wr3    = (const float*)d_in[12];
    const float* att3   = (const float*)d_in[13];
    const float* b3     = (const float*)d_in[14];
    const float* Wlin1  = (const float*)d_in[15];
    const float* blin1  = (const float*)d_in[16];
    const float* Wlin2  = (const float*)d_in[17];
    const float* blin2  = (const float*)d_in[18];
    const float* c1     = (const float*)d_in[19];
    const float* c2     = (const float*)d_in[20];
    float* out = (float*)d_out;

    const int E = in_sizes[1] / 2;   // 504378
    const int N = NODES;

    // ---- workspace carve (bytes), total ~48.9 MB ----
    char* ws = (char*)d_ws;
    // R1 region (17,442,560 B): C1b [N,640]bf16 -> later C2b [N,256]bf16 -> later Cs [N,256]f32
    __hip_bfloat16* C1b = (__hip_bfloat16*)(ws + 0);
    __hip_bfloat16* C2b = (__hip_bfloat16*)(ws + 0);
    float*          Cs  = (float*)(ws + 0);
    __hip_bfloat16* xb  = (__hip_bfloat16*)(ws + 17442560);   // [N,512] bf16
    __hip_bfloat16* h1b = (__hip_bfloat16*)(ws + 31396608);   // [N,320] bf16
    float*          h2  = (float*)(ws + 40117888);            // [N,100] f32
    __hip_bfloat16* W1T = (__hip_bfloat16*)(ws + 45568688);   // [640,512]
    __hip_bfloat16* W2T = (__hip_bfloat16*)(ws + 46224048);   // [256,320]
    __hip_bfloat16* WsT = (__hip_bfloat16*)(ws + 46387888);   // [256,512]
    float*          bcat = (float*)(ws + 46650032);           // [256]
    float*          xl3 = (float*)(ws + 46651056);
    float*          xr3 = (float*)(ws + 46705564);
    int*            ioff = (int*)(ws + 46760072);             // N+1
    int*            cur  = (int*)(ws + 46814584);             // N
    int*            ssrc = (int*)(ws + 46869092);             // E
    float*          lsum = (float*)(ws + 48886604);           // 2

    hipMemsetAsync(cur, 0, sizeof(int) * N, stream);
    hipMemsetAsync(lsum, 0, sizeof(float) * 2, stream);

    // ---- CSR build ----
    hist_kernel<<<(E + 255) / 256, 256, 0, stream>>>(ei + E, cur, E);
    scan_kernel<<<1, 1024, 0, stream>>>(cur, ioff, N);
    scatter_kernel<<<(E + 255) / 256, 256, 0, stream>>>(ei, ei + E, cur, ssrc, E);

    // ---- pack inputs/weights to bf16 ----
    convert_x_kernel<<<(N * 512 + 255) / 256, 256, 0, stream>>>(x, xb, N);
    convert_w1_kernel<<<(640 * 512 + 255) / 256, 256, 0, stream>>>(Wl1, Wr1, W1T);

    // ---- layer 1: C1b[:, :300]=xl1, [:,300:600]=xr1 ----
    mfma_gemm<__hip_bfloat16, false><<<dim3(10, 107), 256, 0, stream>>>(
        xb, W1T, C1b, nullptr, nullptr, N, 512, 640, 640);
    gat_node_kernel<300, 5, 640, 320, __hip_bfloat16, __hip_bfloat16, true>
        <<<(N + 3) / 4, 256, 0, stream>>>(C1b, C1b + 300, att1, b1, ioff, ssrc, h1b, N);

    // ---- layer 2 ----
    convert_w2_kernel<<<(256 * 320 + 255) / 256, 256, 0, stream>>>(Wl2, Wr2, W2T);
    mfma_gemm<__hip_bfloat16, false><<<dim3(4, 107), 256, 0, stream>>>(
        h1b, W2T, C2b, nullptr, nullptr, N, 320, 256, 256);
    gat_node_kernel<100, 2, 256, 100, __hip_bfloat16, float, true>
        <<<(N + 3) / 4, 256, 0, stream>>>(C2b, C2b + 100, att2, b2, ioff, ssrc, h2, N);

    // ---- skip connections: Cs[:, :100]=xo, [:,100:200]=z ----
    convert_ws_kernel<<<(256 * 512 + 255) / 256, 256, 0, stream>>>(Wlin1, Wlin2, WsT);
    convert_bcat_kernel<<<1, 256, 0, stream>>>(blin1, blin2, bcat);
    mfma_gemm<float, true><<<dim3(4, 107), 256, 0, stream>>>(
        xb, WsT, Cs, bcat, h2, N, 512, 256, 256);

    // ---- reconstruction loss ----
    loss_kernel<<<2048, 256, 0, stream>>>(Cs + 100, ei, nei, lsum, E, 256);

    // ---- layer 3 ----
    gemm_vec1_kernel<<<(N + 3) / 4, 256, 0, stream>>>(Cs, Wl3, Wr3, xl3, xr3, N, 256);
    gat3_kernel<<<(N + 255) / 256, 256, 0, stream>>>(xl3, xr3, att3, b3, ioff, ssrc, out, N);

    finalize_kernel<<<1, 1, 0, stream>>>(lsum, c1, c2, out, N, E);
}

// Round 4
// 519.980 us; speedup vs baseline: 1.9259x; 1.0996x over previous
//
#include <hip/hip_runtime.h>
#include <hip/hip_bf16.h>

#define NODES 13627
#define DIM   500

typedef short short8 __attribute__((ext_vector_type(8)));
typedef float f32x4 __attribute__((ext_vector_type(4)));

__device__ inline float wave_reduce_sum(float v) {
#pragma unroll
    for (int o = 32; o > 0; o >>= 1) v += __shfl_xor(v, o, 64);
    return v;
}

__device__ inline float tof(float v) { return v; }
__device__ inline float tof(__hip_bfloat16 v) { return __bfloat162float(v); }
__device__ inline void store_v(float* p, float v) { *p = v; }
__device__ inline void store_v(__hip_bfloat16* p, float v) { *p = __float2bfloat16(v); }

// bf16 (packed pair in uint) -> f32, exact
__device__ inline float blo(unsigned w) { unsigned t = w << 16;        return __builtin_bit_cast(float, t); }
__device__ inline float bhi(unsigned w) { unsigned t = w & 0xffff0000u; return __builtin_bit_cast(float, t); }

// ---------------------------------------------------------------------------
// CSR build: histogram -> scan -> scatter
// ---------------------------------------------------------------------------
__global__ __launch_bounds__(256) void hist_kernel(const int* __restrict__ dst,
                                                   int* __restrict__ cnt, int E) {
    int i = blockIdx.x * blockDim.x + threadIdx.x;
    if (i < E) atomicAdd(&cnt[dst[i]], 1);
}

__global__ __launch_bounds__(1024) void scan_kernel(int* __restrict__ cnt_cur,
                                                    int* __restrict__ off, int n) {
    __shared__ int wsum[16];
    const int tid = threadIdx.x, lane = tid & 63, w = tid >> 6;
    int carry = 0;
    for (int base = 0; base < n; base += 1024) {
        int i = base + tid;
        int v = (i < n) ? cnt_cur[i] : 0;
        int s = v;
#pragma unroll
        for (int o = 1; o < 64; o <<= 1) {
            int t = __shfl_up(s, o, 64);
            if (lane >= o) s += t;
        }
        if (lane == 63) wsum[w] = s;
        __syncthreads();
        if (w == 0 && lane < 16) {
            int x = wsum[lane];
            int sx = x;
#pragma unroll
            for (int o = 1; o < 16; o <<= 1) {
                int t = __shfl_up(sx, o, 64);
                if (lane >= o) sx += t;
            }
            wsum[lane] = sx;            // inclusive wave-sum prefix
        }
        __syncthreads();
        int wo = (w == 0) ? 0 : wsum[w - 1];
        int total = wsum[15];
        int excl = carry + wo + (s - v);
        if (i < n) { off[i] = excl; cnt_cur[i] = excl; }
        carry += total;
        __syncthreads();                // protect wsum before next chunk
    }
    if (tid == 0) off[n] = carry;
}

__global__ __launch_bounds__(256) void scatter_kernel(const int* __restrict__ src,
                                                      const int* __restrict__ dst,
                                                      int* __restrict__ cur,
                                                      int* __restrict__ ssrc, int E) {
    int i = blockIdx.x * blockDim.x + threadIdx.x;
    if (i < E) {
        int p = atomicAdd(&cur[dst[i]], 1);
        ssrc[p] = src[i];
    }
}

// ---------------------------------------------------------------------------
// Conversion / packing
// ---------------------------------------------------------------------------
struct b4 { __hip_bfloat16 a, b, c, d; };

__global__ __launch_bounds__(256) void convert_x_kernel(const float* __restrict__ x,
                                                        __hip_bfloat16* __restrict__ xb, int M) {
    int i = blockIdx.x * 256 + threadIdx.x;      // group of 4 cols
    if (i >= M * 128) return;
    int m = i >> 7, k = (i & 127) << 2;
    b4 o;
    if (k < 500) {
        float4 v = *(const float4*)(x + (size_t)m * 500 + k);
        o.a = __float2bfloat16(v.x); o.b = __float2bfloat16(v.y);
        o.c = __float2bfloat16(v.z); o.d = __float2bfloat16(v.w);
    } else {
        o.a = o.b = o.c = o.d = __float2bfloat16(0.f);
    }
    *(b4*)(xb + (size_t)m * 512 + k) = o;
}

// Fused weight packing:
//  W1T[640][512]: n<300 Wl1[k][n], n<600 Wr1[k][n-300]      (327,680 elems)
//  W2T[256][320]: n<100 Wl2[k][n], n<200 Wr2[k][n-100]      ( 81,920)
//  WsT[256][512]: n<100 Wlin1[k][n], n<200 Wlin2[k][n-100]  (131,072)
//  bcat[256] f32: blin1 | blin2                             (    256)
__global__ __launch_bounds__(256) void convert_weights_kernel(
    const float* __restrict__ Wl1, const float* __restrict__ Wr1,
    const float* __restrict__ Wl2, const float* __restrict__ Wr2,
    const float* __restrict__ Ws1, const float* __restrict__ Ws2,
    const float* __restrict__ bs1, const float* __restrict__ bs2,
    __hip_bfloat16* __restrict__ W1T, __hip_bfloat16* __restrict__ W2T,
    __hip_bfloat16* __restrict__ WsT, float* __restrict__ bcat) {
    int i = blockIdx.x * 256 + threadIdx.x;
    if (i < 327680) {
        int n = i >> 9, k = i & 511;
        float v = 0.f;
        if (k < 500) {
            if (n < 300) v = Wl1[k * 300 + n];
            else if (n < 600) v = Wr1[k * 300 + n - 300];
        }
        W1T[i] = __float2bfloat16(v);
    } else if (i < 409600) {
        int j = i - 327680;
        int n = j / 320, k = j - n * 320;
        float v = 0.f;
        if (k < 300) {
            if (n < 100) v = Wl2[k * 100 + n];
            else if (n < 200) v = Wr2[k * 100 + n - 100];
        }
        W2T[j] = __float2bfloat16(v);
    } else if (i < 540672) {
        int j = i - 409600;
        int n = j >> 9, k = j & 511;
        float v = 0.f;
        if (k < 500) {
            if (n < 100) v = Ws1[k * 100 + n];
            else if (n < 200) v = Ws2[k * 100 + n - 100];
        }
        WsT[j] = __float2bfloat16(v);
    } else if (i < 540928) {
        int n = i - 540672;
        float v = 0.f;
        if (n < 100) v = bs1[n];
        else if (n < 200) v = bs2[n - 100];
        bcat[n] = v;
    }
}

// ---------------------------------------------------------------------------
// bf16 MFMA GEMM: C[M,Nn] = A[M,Kp] @ BT[Nn,Kp]^T
// BM=128, BN=64, BK=32; 256 threads = 4 waves.
// SKIP epilogue: val = relu(acc+bias[gn]) + h2[gm][gn%100];
//   gn<100 -> xo f32 [N,100];  100<=gn<200 -> zb bf16 [N,128];
//   200<=gn<228 -> zb zero-pad.
// ---------------------------------------------------------------------------
template <typename TC, bool SKIP>
__global__ __launch_bounds__(256) void mfma_gemm(
    const __hip_bfloat16* __restrict__ A, const __hip_bfloat16* __restrict__ BT,
    TC* __restrict__ C, const float* __restrict__ bias, const float* __restrict__ h2,
    __hip_bfloat16* __restrict__ zb, int M, int Kp, int Nn, int ldc) {
    __shared__ short AsF[8 * 64 * 8];
    __shared__ short BsF[4 * 64 * 8];
    const int t = threadIdx.x;
    const int w = t >> 6, lane = t & 63;
    const int c = t & 3, rr = t >> 2;
    const int m0 = blockIdx.y * 128, n0 = blockIdx.x * 64;

    f32x4 acc[2][4];
#pragma unroll
    for (int i = 0; i < 2; i++)
#pragma unroll
        for (int j = 0; j < 4; j++) acc[i][j] = (f32x4){0.f, 0.f, 0.f, 0.f};

    for (int k0 = 0; k0 < Kp; k0 += 32) {
#pragma unroll
        for (int r = 0; r < 2; r++) {
            int m = r * 64 + rr;
            int gm = m0 + m; if (gm >= M) gm = M - 1;
            float4 v = *(const float4*)(A + (size_t)gm * Kp + k0 + c * 8);
            int mi = m >> 4, sl = m & 15;
            *(float4*)(&AsF[(mi * 64 + c * 16 + sl) * 8]) = v;
        }
        {
            int n = rr;
            float4 v = *(const float4*)(BT + (size_t)(n0 + n) * Kp + k0 + c * 8);
            int ni = n >> 4, sl = n & 15;
            *(float4*)(&BsF[(ni * 64 + c * 16 + sl) * 8]) = v;
        }
        __syncthreads();
        short8 a0 = *(const short8*)(&AsF[((w * 2 + 0) * 64 + lane) * 8]);
        short8 a1 = *(const short8*)(&AsF[((w * 2 + 1) * 64 + lane) * 8]);
#pragma unroll
        for (int j = 0; j < 4; j++) {
            short8 b = *(const short8*)(&BsF[(j * 64 + lane) * 8]);
            acc[0][j] = __builtin_amdgcn_mfma_f32_16x16x32_bf16(a0, b, acc[0][j], 0, 0, 0);
            acc[1][j] = __builtin_amdgcn_mfma_f32_16x16x32_bf16(a1, b, acc[1][j], 0, 0, 0);
        }
        __syncthreads();
    }

    const int q = lane >> 4, sl = lane & 15;
#pragma unroll
    for (int i = 0; i < 2; i++) {
#pragma unroll
        for (int j = 0; j < 4; j++) {
#pragma unroll
            for (int reg = 0; reg < 4; reg++) {
                int gm = m0 + w * 32 + i * 16 + q * 4 + reg;
                int gn = n0 + j * 16 + sl;
                if (gm >= M) continue;
                float v = acc[i][j][reg];
                if constexpr (SKIP) {
                    if (gn < 200) {
                        int cn = gn < 100 ? gn : gn - 100;
                        float val = fmaxf(v + bias[gn], 0.f) + h2[(size_t)gm * 100 + cn];
                        if (gn < 100) C[(size_t)gm * 100 + gn] = val;
                        else zb[(size_t)gm * 128 + (gn - 100)] = __float2bfloat16(val);
                    } else if (gn < 228) {
                        zb[(size_t)gm * 128 + (gn - 100)] = __float2bfloat16(0.f);
                    }
                } else {
                    store_v(&C[(size_t)gm * ldc + gn], v);
                }
            }
        }
    }
}

// ---------------------------------------------------------------------------
// GATv2 edge+aggregate, one wave per dst node, single-pass softmax.
// ---------------------------------------------------------------------------
template <int F, int FPL, int SIN, int SOUT, typename TIN, typename TOUT, bool RELU>
__global__ __launch_bounds__(256) void gat_node_kernel(
    const TIN* __restrict__ xl, const TIN* __restrict__ xr,
    const float* __restrict__ att, const float* __restrict__ bias,
    const int* __restrict__ off, const int* __restrict__ ssrc,
    TOUT* __restrict__ out, int n) {
    const int wid = blockIdx.x * 4 + (threadIdx.x >> 6);
    const int lane = threadIdx.x & 63;
    if (wid >= n) return;

    float attv[FPL], xrv[FPL], acc[FPL];
#pragma unroll
    for (int k = 0; k < FPL; k++) {
        int f = lane + 64 * k;
        bool ok = f < F;
        attv[k] = ok ? att[f] : 0.f;
        xrv[k]  = ok ? tof(xr[(size_t)wid * SIN + f]) : 0.f;
        acc[k] = 0.f;
    }
    float den = 0.f;
    const int s0 = off[wid], s1 = off[wid + 1];
    for (int e = s0 - 1; e < s1; e++) {
        int src = (e < s0) ? wid : ssrc[e];
        float xlv[FPL];
        float p = 0.f;
#pragma unroll
        for (int k = 0; k < FPL; k++) {
            int f = lane + 64 * k;
            xlv[k] = (f < F) ? tof(xl[(size_t)src * SIN + f]) : 0.f;
            float tt = xlv[k] + xrv[k];
            float g = tt > 0.f ? tt : 0.2f * tt;
            p += attv[k] * g;
        }
        p = wave_reduce_sum(p);
        float ex = expf(p);
        den += ex;
#pragma unroll
        for (int k = 0; k < FPL; k++) acc[k] += ex * xlv[k];
    }
    float inv = 1.f / (den + 1e-16f);
#pragma unroll
    for (int k = 0; k < FPL; k++) {
        int f = lane + 64 * k;
        if (f < SOUT) {
            float v = 0.f;
            if (f < F) {
                v = acc[k] * inv + bias[f];
                if (RELU) v = fmaxf(v, 0.f);
            }
            store_v(&out[(size_t)wid * SOUT + f], v);
        }
    }
}

// ---------------------------------------------------------------------------
// Layer-3 projections: xl3 = xo @ Wl3, xr3 = xo @ Wr3   (K=100)
// ---------------------------------------------------------------------------
__global__ __launch_bounds__(256) void gemm_vec1_kernel(
    const float* __restrict__ xo, const float* __restrict__ wl,
    const float* __restrict__ wr, float* __restrict__ xl3,
    float* __restrict__ xr3, int M, int ldx) {
    const int wid = blockIdx.x * 4 + (threadIdx.x >> 6);
    const int lane = threadIdx.x & 63;
    if (wid >= M) return;
    float a = 0.f, b = 0.f;
    for (int f = lane; f < 100; f += 64) {
        float v = xo[(size_t)wid * ldx + f];
        a += v * wl[f];
        b += v * wr[f];
    }
    a = wave_reduce_sum(a);
    b = wave_reduce_sum(b);
    if (lane == 0) { xl3[wid] = a; xr3[wid] = b; }
}

__global__ __launch_bounds__(256) void gat3_kernel(
    const float* __restrict__ xl3, const float* __restrict__ xr3,
    const float* __restrict__ att3, const float* __restrict__ b3,
    const int* __restrict__ off, const int* __restrict__ ssrc,
    float* __restrict__ out, int n) {
    int i = blockIdx.x * blockDim.x + threadIdx.x;
    if (i >= n) return;
    const float xrv = xr3[i];
    const float att = att3[0];
    float num = 0.f, den = 0.f;
    const int s0 = off[i], s1 = off[i + 1];
    for (int e = s0 - 1; e < s1; e++) {
        int src = (e < s0) ? i : ssrc[e];
        float xlv = xl3[src];
        float t = xlv + xrv;
        float g = t > 0.f ? t : 0.2f * t;
        float ex = expf(g * att);
        den += ex;
        num += ex * xlv;
    }
    out[i] = num / (den + 1e-16f) + b3[0];
}

// ---------------------------------------------------------------------------
// Link-prediction loss on bf16 z [N,128] (3.49 MB -> fits per-XCD L2).
// 16 lanes/item (4 items/wave), uint4 = 8 bf16 per lane, 2-way interleave.
// ---------------------------------------------------------------------------
__global__ __launch_bounds__(256) void loss_kernel(
    const __hip_bfloat16* __restrict__ zb, const int* __restrict__ pos,
    const int* __restrict__ neg, float* __restrict__ lsum, int E) {
    const int lane = threadIdx.x & 63;
    const int sl = lane & 15;
    const int wlocal = threadIdx.x >> 6;
    const int q = lane >> 4;
    const int nq = gridDim.x * 16;
    const int qid = (blockIdx.x * 4 + wlocal) * 4 + q;
    const int total = 2 * E;
    float psum = 0.f, nsum = 0.f;

    for (int base = qid; base < total; base += 2 * nq) {
        uint4 au[2], bu[2];
        bool act[2], isN[2];
#pragma unroll
        for (int s = 0; s < 2; s++) {
            int it = base + s * nq;
            act[s] = it < total;
            int itc = act[s] ? it : 0;
            isN[s] = itc >= E;
            int e = isN[s] ? itc - E : itc;
            const int* ei = isN[s] ? neg : pos;
            int u = ei[e], v = ei[E + e];
            au[s] = *(const uint4*)(zb + (size_t)u * 128 + sl * 8);
            bu[s] = *(const uint4*)(zb + (size_t)v * 128 + sl * 8);
        }
#pragma unroll
        for (int s = 0; s < 2; s++) {
            float p = blo(au[s].x) * blo(bu[s].x) + bhi(au[s].x) * bhi(bu[s].x)
                    + blo(au[s].y) * blo(bu[s].y) + bhi(au[s].y) * bhi(bu[s].y)
                    + blo(au[s].z) * blo(bu[s].z) + bhi(au[s].z) * bhi(bu[s].z)
                    + blo(au[s].w) * blo(bu[s].w) + bhi(au[s].w) * bhi(bu[s].w);
            p += __shfl_xor(p, 1, 64);
            p += __shfl_xor(p, 2, 64);
            p += __shfl_xor(p, 4, 64);
            p += __shfl_xor(p, 8, 64);
            if (sl == 0 && act[s]) {
                float sig = 1.f / (1.f + expf(-p));
                if (isN[s]) nsum += logf(1.f - sig + 1e-15f);
                else        psum += logf(sig + 1e-15f);
            }
        }
    }
    float pw = wave_reduce_sum(psum);
    float nw = wave_reduce_sum(nsum);
    __shared__ float sp[4], sn[4];
    if (lane == 0) { sp[wlocal] = pw; sn[wlocal] = nw; }
    __syncthreads();
    if (threadIdx.x == 0) {
        atomicAdd(&lsum[0], sp[0] + sp[1] + sp[2] + sp[3]);
        atomicAdd(&lsum[1], sn[0] + sn[1] + sn[2] + sn[3]);
    }
}

__global__ void finalize_kernel(const float* __restrict__ lsum,
                                const float* __restrict__ c1,
                                const float* __restrict__ c2,
                                float* __restrict__ out, int n, int E) {
    out[n]     = -(lsum[0] + lsum[1]) / (float)E;
    out[n + 1] = c1[0];
    out[n + 2] = c2[0];
}

// ---------------------------------------------------------------------------
extern "C" void kernel_launch(void* const* d_in, const int* in_sizes, int n_in,
                              void* d_out, int out_size, void* d_ws, size_t ws_size,
                              hipStream_t stream) {
    const float* x      = (const float*)d_in[0];
    const int*   ei     = (const int*)d_in[1];
    const int*   nei    = (const int*)d_in[2];
    const float* Wl1    = (const float*)d_in[3];
    const float* Wr1    = (const float*)d_in[4];
    const float* att1   = (const float*)d_in[5];
    const float* b1     = (const float*)d_in[6];
    const float* Wl2    = (const float*)d_in[7];
    const float* Wr2    = (const float*)d_in[8];
    const float* att2   = (const float*)d_in[9];
    const float* b2     = (const float*)d_in[10];
    const float* Wl3    = (const float*)d_in[11];
    const float* Wr3    = (const float*)d_in[12];
    const float* att3   = (const float*)d_in[13];
    const float* b3     = (const float*)d_in[14];
    const float* Wlin1  = (const float*)d_in[15];
    const float* blin1  = (const float*)d_in[16];
    const float* Wlin2  = (const float*)d_in[17];
    const float* blin2  = (const float*)d_in[18];
    const float* c1     = (const float*)d_in[19];
    const float* c2     = (const float*)d_in[20];
    float* out = (float*)d_out;

    const int E = in_sizes[1] / 2;   // 504378
    const int N = NODES;

    // ---- workspace carve (bytes), ~48.9 MB ----
    char* ws = (char*)d_ws;
    // R1 region: C1b [N,640]bf16; later C2b [N,256]bf16 @0, xo f32 [N,100] @7,000,064,
    //            zb bf16 [N,128] @12,451,072 (all dead/live windows disjoint)
    __hip_bfloat16* C1b = (__hip_bfloat16*)(ws + 0);
    __hip_bfloat16* C2b = (__hip_bfloat16*)(ws + 0);
    float*          xo  = (float*)(ws + 7000064);
    __hip_bfloat16* zb  = (__hip_bfloat16*)(ws + 12451072);
    __hip_bfloat16* xb  = (__hip_bfloat16*)(ws + 17442560);   // [N,512] bf16
    __hip_bfloat16* h1b = (__hip_bfloat16*)(ws + 31396608);   // [N,320] bf16
    float*          h2  = (float*)(ws + 40117888);            // [N,100] f32
    __hip_bfloat16* W1T = (__hip_bfloat16*)(ws + 45568688);   // [640,512]
    __hip_bfloat16* W2T = (__hip_bfloat16*)(ws + 46224048);   // [256,320]
    __hip_bfloat16* WsT = (__hip_bfloat16*)(ws + 46387888);   // [256,512]
    float*          bcat = (float*)(ws + 46650032);           // [256]
    float*          xl3 = (float*)(ws + 46651056);
    float*          xr3 = (float*)(ws + 46705564);
    int*            ioff = (int*)(ws + 46760072);             // N+1
    int*            cur  = (int*)(ws + 46814584);             // N
    int*            ssrc = (int*)(ws + 46869092);             // E
    float*          lsum = (float*)(ws + 48886604);           // 2

    hipMemsetAsync(cur, 0, sizeof(int) * N, stream);
    hipMemsetAsync(lsum, 0, sizeof(float) * 2, stream);

    // ---- CSR build ----
    hist_kernel<<<(E + 255) / 256, 256, 0, stream>>>(ei + E, cur, E);
    scan_kernel<<<1, 1024, 0, stream>>>(cur, ioff, N);
    scatter_kernel<<<(E + 255) / 256, 256, 0, stream>>>(ei, ei + E, cur, ssrc, E);

    // ---- pack inputs/weights ----
    convert_x_kernel<<<(N * 128 + 255) / 256, 256, 0, stream>>>(x, xb, N);
    convert_weights_kernel<<<(540928 + 255) / 256, 256, 0, stream>>>(
        Wl1, Wr1, Wl2, Wr2, Wlin1, Wlin2, blin1, blin2, W1T, W2T, WsT, bcat);

    // ---- layer 1 ----
    mfma_gemm<__hip_bfloat16, false><<<dim3(10, 107), 256, 0, stream>>>(
        xb, W1T, C1b, nullptr, nullptr, nullptr, N, 512, 640, 640);
    gat_node_kernel<300, 5, 640, 320, __hip_bfloat16, __hip_bfloat16, true>
        <<<(N + 3) / 4, 256, 0, stream>>>(C1b, C1b + 300, att1, b1, ioff, ssrc, h1b, N);

    // ---- layer 2 ----
    mfma_gemm<__hip_bfloat16, false><<<dim3(4, 107), 256, 0, stream>>>(
        h1b, W2T, C2b, nullptr, nullptr, nullptr, N, 320, 256, 256);
    gat_node_kernel<100, 2, 256, 100, __hip_bfloat16, float, true>
        <<<(N + 3) / 4, 256, 0, stream>>>(C2b, C2b + 100, att2, b2, ioff, ssrc, h2, N);

    // ---- skip connections: xo f32 [N,100], zb bf16 [N,128] ----
    mfma_gemm<float, true><<<dim3(4, 107), 256, 0, stream>>>(
        xb, WsT, xo, bcat, h2, zb, N, 512, 256, 0);

    // ---- reconstruction loss ----
    loss_kernel<<<2048, 256, 0, stream>>>(zb, ei, nei, lsum, E);

    // ---- layer 3 ----
    gemm_vec1_kernel<<<(N + 3) / 4, 256, 0, stream>>>(xo, Wl3, Wr3, xl3, xr3, N, 100);
    gat3_kernel<<<(N + 255) / 256, 256, 0, stream>>>(xl3, xr3, att3, b3, ioff, ssrc, out, N);

    finalize_kernel<<<1, 1, 0, stream>>>(lsum, c1, c2, out, N, E);
}

// Round 5
// 477.888 us; speedup vs baseline: 2.0955x; 1.0881x over previous
//
#include <hip/hip_runtime.h>
#include <hip/hip_bf16.h>

#define NODES 13627
#define DIM   500

typedef short short8 __attribute__((ext_vector_type(8)));
typedef float f32x4 __attribute__((ext_vector_type(4)));

__device__ inline float wave_reduce_sum(float v) {
#pragma unroll
    for (int o = 32; o > 0; o >>= 1) v += __shfl_xor(v, o, 64);
    return v;
}

__device__ inline float tof(float v) { return v; }
__device__ inline float tof(__hip_bfloat16 v) { return __bfloat162float(v); }
__device__ inline void store_v(float* p, float v) { *p = v; }
__device__ inline void store_v(__hip_bfloat16* p, float v) { *p = __float2bfloat16(v); }

// bf16 (packed pair in uint) -> f32, exact
__device__ inline float blo(unsigned w) { unsigned t = w << 16;        return __builtin_bit_cast(float, t); }
__device__ inline float bhi(unsigned w) { unsigned t = w & 0xffff0000u; return __builtin_bit_cast(float, t); }

// ---------------------------------------------------------------------------
// CSR build: histogram -> scan -> scatter
// ---------------------------------------------------------------------------
__global__ __launch_bounds__(256) void hist_kernel(const int* __restrict__ dst,
                                                   int* __restrict__ cnt, int E) {
    int i = blockIdx.x * blockDim.x + threadIdx.x;
    if (i < E) atomicAdd(&cnt[dst[i]], 1);
}

__global__ __launch_bounds__(1024) void scan_kernel(int* __restrict__ cnt_cur,
                                                    int* __restrict__ off, int n) {
    __shared__ int wsum[16];
    const int tid = threadIdx.x, lane = tid & 63, w = tid >> 6;
    int carry = 0;
    for (int base = 0; base < n; base += 1024) {
        int i = base + tid;
        int v = (i < n) ? cnt_cur[i] : 0;
        int s = v;
#pragma unroll
        for (int o = 1; o < 64; o <<= 1) {
            int t = __shfl_up(s, o, 64);
            if (lane >= o) s += t;
        }
        if (lane == 63) wsum[w] = s;
        __syncthreads();
        if (w == 0 && lane < 16) {
            int x = wsum[lane];
            int sx = x;
#pragma unroll
            for (int o = 1; o < 16; o <<= 1) {
                int t = __shfl_up(sx, o, 64);
                if (lane >= o) sx += t;
            }
            wsum[lane] = sx;
        }
        __syncthreads();
        int wo = (w == 0) ? 0 : wsum[w - 1];
        int total = wsum[15];
        int excl = carry + wo + (s - v);
        if (i < n) { off[i] = excl; cnt_cur[i] = excl; }
        carry += total;
        __syncthreads();
    }
    if (tid == 0) off[n] = carry;
}

__global__ __launch_bounds__(256) void scatter_kernel(const int* __restrict__ src,
                                                      const int* __restrict__ dst,
                                                      int* __restrict__ cur,
                                                      int* __restrict__ ssrc, int E) {
    int i = blockIdx.x * blockDim.x + threadIdx.x;
    if (i < E) {
        int p = atomicAdd(&cur[dst[i]], 1);
        ssrc[p] = src[i];
    }
}

// ---------------------------------------------------------------------------
// Fused conversion / packing (weights + bias + x) in ONE launch.
//  [0, 327680)            W1T[640][512]
//  [327680, 409600)       W2T[256][320]
//  [409600, 540672)       WsT[256][512]
//  [540672, 540928)       bcat[256]
//  [540928, +N*128)       xb [N,512] bf16 (4 cols per thread)
// ---------------------------------------------------------------------------
struct b4 { __hip_bfloat16 a, b, c, d; };

__global__ __launch_bounds__(256) void convert_all_kernel(
    const float* __restrict__ x,
    const float* __restrict__ Wl1, const float* __restrict__ Wr1,
    const float* __restrict__ Wl2, const float* __restrict__ Wr2,
    const float* __restrict__ Ws1, const float* __restrict__ Ws2,
    const float* __restrict__ bs1, const float* __restrict__ bs2,
    __hip_bfloat16* __restrict__ W1T, __hip_bfloat16* __restrict__ W2T,
    __hip_bfloat16* __restrict__ WsT, float* __restrict__ bcat,
    __hip_bfloat16* __restrict__ xb, int M) {
    int i = blockIdx.x * 256 + threadIdx.x;
    if (i < 327680) {
        int n = i >> 9, k = i & 511;
        float v = 0.f;
        if (k < 500) {
            if (n < 300) v = Wl1[k * 300 + n];
            else if (n < 600) v = Wr1[k * 300 + n - 300];
        }
        W1T[i] = __float2bfloat16(v);
    } else if (i < 409600) {
        int j = i - 327680;
        int n = j / 320, k = j - n * 320;
        float v = 0.f;
        if (k < 300) {
            if (n < 100) v = Wl2[k * 100 + n];
            else if (n < 200) v = Wr2[k * 100 + n - 100];
        }
        W2T[j] = __float2bfloat16(v);
    } else if (i < 540672) {
        int j = i - 409600;
        int n = j >> 9, k = j & 511;
        float v = 0.f;
        if (k < 500) {
            if (n < 100) v = Ws1[k * 100 + n];
            else if (n < 200) v = Ws2[k * 100 + n - 100];
        }
        WsT[j] = __float2bfloat16(v);
    } else if (i < 540928) {
        int n = i - 540672;
        float v = 0.f;
        if (n < 100) v = bs1[n];
        else if (n < 200) v = bs2[n - 100];
        bcat[n] = v;
    } else {
        int j = i - 540928;
        if (j >= M * 128) return;
        int m = j >> 7, k = (j & 127) << 2;
        b4 o;
        if (k < 500) {
            float4 v = *(const float4*)(x + (size_t)m * 500 + k);
            o.a = __float2bfloat16(v.x); o.b = __float2bfloat16(v.y);
            o.c = __float2bfloat16(v.z); o.d = __float2bfloat16(v.w);
        } else {
            o.a = o.b = o.c = o.d = __float2bfloat16(0.f);
        }
        *(b4*)(xb + (size_t)m * 512 + k) = o;
    }
}

// ---------------------------------------------------------------------------
// bf16 MFMA GEMM: C[M,Nn] = A[M,Kp] @ BT[Nn,Kp]^T
// BM=128, BN=64, BK=32; 256 threads = 4 waves.
// SKIP epilogue: val = relu(acc+bias[gn]) + h2[gm][gn%100];
//   gn<100 -> xo f32 [N,100];  100<=gn<200 -> zb bf16 [N,128];
//   200<=gn<228 -> zb zero-pad.
// ---------------------------------------------------------------------------
template <typename TC, bool SKIP>
__global__ __launch_bounds__(256) void mfma_gemm(
    const __hip_bfloat16* __restrict__ A, const __hip_bfloat16* __restrict__ BT,
    TC* __restrict__ C, const float* __restrict__ bias, const float* __restrict__ h2,
    __hip_bfloat16* __restrict__ zb, int M, int Kp, int Nn, int ldc) {
    __shared__ short AsF[8 * 64 * 8];
    __shared__ short BsF[4 * 64 * 8];
    const int t = threadIdx.x;
    const int w = t >> 6, lane = t & 63;
    const int c = t & 3, rr = t >> 2;
    const int m0 = blockIdx.y * 128, n0 = blockIdx.x * 64;

    f32x4 acc[2][4];
#pragma unroll
    for (int i = 0; i < 2; i++)
#pragma unroll
        for (int j = 0; j < 4; j++) acc[i][j] = (f32x4){0.f, 0.f, 0.f, 0.f};

    for (int k0 = 0; k0 < Kp; k0 += 32) {
#pragma unroll
        for (int r = 0; r < 2; r++) {
            int m = r * 64 + rr;
            int gm = m0 + m; if (gm >= M) gm = M - 1;
            float4 v = *(const float4*)(A + (size_t)gm * Kp + k0 + c * 8);
            int mi = m >> 4, sl = m & 15;
            *(float4*)(&AsF[(mi * 64 + c * 16 + sl) * 8]) = v;
        }
        {
            int n = rr;
            float4 v = *(const float4*)(BT + (size_t)(n0 + n) * Kp + k0 + c * 8);
            int ni = n >> 4, sl = n & 15;
            *(float4*)(&BsF[(ni * 64 + c * 16 + sl) * 8]) = v;
        }
        __syncthreads();
        short8 a0 = *(const short8*)(&AsF[((w * 2 + 0) * 64 + lane) * 8]);
        short8 a1 = *(const short8*)(&AsF[((w * 2 + 1) * 64 + lane) * 8]);
#pragma unroll
        for (int j = 0; j < 4; j++) {
            short8 b = *(const short8*)(&BsF[(j * 64 + lane) * 8]);
            acc[0][j] = __builtin_amdgcn_mfma_f32_16x16x32_bf16(a0, b, acc[0][j], 0, 0, 0);
            acc[1][j] = __builtin_amdgcn_mfma_f32_16x16x32_bf16(a1, b, acc[1][j], 0, 0, 0);
        }
        __syncthreads();
    }

    const int q = lane >> 4, sl = lane & 15;
#pragma unroll
    for (int i = 0; i < 2; i++) {
#pragma unroll
        for (int j = 0; j < 4; j++) {
#pragma unroll
            for (int reg = 0; reg < 4; reg++) {
                int gm = m0 + w * 32 + i * 16 + q * 4 + reg;
                int gn = n0 + j * 16 + sl;
                if (gm >= M) continue;
                float v = acc[i][j][reg];
                if constexpr (SKIP) {
                    if (gn < 200) {
                        int cn = gn < 100 ? gn : gn - 100;
                        float val = fmaxf(v + bias[gn], 0.f) + h2[(size_t)gm * 100 + cn];
                        if (gn < 100) C[(size_t)gm * 100 + gn] = val;
                        else zb[(size_t)gm * 128 + (gn - 100)] = __float2bfloat16(val);
                    } else if (gn < 228) {
                        zb[(size_t)gm * 128 + (gn - 100)] = __float2bfloat16(0.f);
                    }
                } else {
                    store_v(&C[(size_t)gm * ldc + gn], v);
                }
            }
        }
    }
}

// ---------------------------------------------------------------------------
// GATv2 edge+aggregate. TWO waves per dst node (edge range split between the
// pair, partial (den,acc) combined through LDS — exact, since this softmax
// formulation needs no max/rescale), 2-edge interleave inside each wave.
// Block = 256 threads = 4 waves = 2 nodes.
// ---------------------------------------------------------------------------
template <int F, int FPL, int SIN, int SOUT, typename TIN, typename TOUT, bool RELU>
__global__ __launch_bounds__(256) void gat_node_kernel(
    const TIN* __restrict__ xl, const TIN* __restrict__ xr,
    const float* __restrict__ att, const float* __restrict__ bias,
    const int* __restrict__ off, const int* __restrict__ ssrc,
    TOUT* __restrict__ out, int n) {
    __shared__ float sden[2];
    __shared__ float sacc[2][FPL * 64];
    const int t = threadIdx.x;
    const int lane = t & 63;
    const int half = (t >> 6) & 1;      // wave within pair
    const int pairIdx = t >> 7;         // pair within block (0..1)
    int wid = blockIdx.x * 2 + pairIdx;
    if (wid >= n) wid = n - 1;          // clamp; duplicate writes are identical

    float attv[FPL], xrv[FPL], acc[FPL];
#pragma unroll
    for (int k = 0; k < FPL; k++) {
        int f = lane + 64 * k;
        bool ok = f < F;
        attv[k] = ok ? att[f] : 0.f;
        xrv[k]  = ok ? tof(xr[(size_t)wid * SIN + f]) : 0.f;
        acc[k] = 0.f;
    }
    const int s0 = off[wid], s1 = off[wid + 1];
    const int h0 = (s1 - s0) >> 1;      // wave0: self-loop + h0 edges; wave1: rest
    const int eb = half ? (s0 + h0) : (s0 - 1);
    const int ee = half ? s1 : (s0 + h0);
    float den = 0.f;

    for (int e = eb; e < ee; e += 2) {
        int srcA = (e < s0) ? wid : ssrc[e];
        bool hasB = (e + 1 < ee);
        int srcB = hasB ? ssrc[e + 1] : srcA;
        float xlvA[FPL], xlvB[FPL];
        float pA = 0.f, pB = 0.f;
#pragma unroll
        for (int k = 0; k < FPL; k++) {
            int f = lane + 64 * k;
            xlvA[k] = (f < F) ? tof(xl[(size_t)srcA * SIN + f]) : 0.f;
            xlvB[k] = (f < F) ? tof(xl[(size_t)srcB * SIN + f]) : 0.f;
            float tA = xlvA[k] + xrv[k];
            float tB = xlvB[k] + xrv[k];
            pA += attv[k] * (tA > 0.f ? tA : 0.2f * tA);
            pB += attv[k] * (tB > 0.f ? tB : 0.2f * tB);
        }
#pragma unroll
        for (int o = 32; o > 0; o >>= 1) {
            pA += __shfl_xor(pA, o, 64);
            pB += __shfl_xor(pB, o, 64);
        }
        float exA = expf(pA);
        den += exA;
#pragma unroll
        for (int k = 0; k < FPL; k++) acc[k] += exA * xlvA[k];
        if (hasB) {
            float exB = expf(pB);
            den += exB;
#pragma unroll
            for (int k = 0; k < FPL; k++) acc[k] += exB * xlvB[k];
        }
    }

    // cross-wave combine (wave1 -> LDS, wave0 adds and writes)
    if (half == 1) {
        if (lane == 0) sden[pairIdx] = den;
#pragma unroll
        for (int k = 0; k < FPL; k++) sacc[pairIdx][k * 64 + lane] = acc[k];
    }
    __syncthreads();
    if (half == 0) {
        den += sden[pairIdx];
#pragma unroll
        for (int k = 0; k < FPL; k++) acc[k] += sacc[pairIdx][k * 64 + lane];
        float inv = 1.f / (den + 1e-16f);
#pragma unroll
        for (int k = 0; k < FPL; k++) {
            int f = lane + 64 * k;
            if (f < SOUT) {
                float v = 0.f;
                if (f < F) {
                    v = acc[k] * inv + bias[f];
                    if (RELU) v = fmaxf(v, 0.f);
                }
                store_v(&out[(size_t)wid * SOUT + f], v);
            }
        }
    }
}

// ---------------------------------------------------------------------------
// Layer-3 projections: xl3 = xo @ Wl3, xr3 = xo @ Wr3   (K=100)
// ---------------------------------------------------------------------------
__global__ __launch_bounds__(256) void gemm_vec1_kernel(
    const float* __restrict__ xo, const float* __restrict__ wl,
    const float* __restrict__ wr, float* __restrict__ xl3,
    float* __restrict__ xr3, int M, int ldx) {
    const int wid = blockIdx.x * 4 + (threadIdx.x >> 6);
    const int lane = threadIdx.x & 63;
    if (wid >= M) return;
    float a = 0.f, b = 0.f;
    for (int f = lane; f < 100; f += 64) {
        float v = xo[(size_t)wid * ldx + f];
        a += v * wl[f];
        b += v * wr[f];
    }
    a = wave_reduce_sum(a);
    b = wave_reduce_sum(b);
    if (lane == 0) { xl3[wid] = a; xr3[wid] = b; }
}

// ---------------------------------------------------------------------------
// Layer-3 GAT (F=1): WAVE per node, lanes parallel over edges.
// ---------------------------------------------------------------------------
__global__ __launch_bounds__(256) void gat3_kernel(
    const float* __restrict__ xl3, const float* __restrict__ xr3,
    const float* __restrict__ att3, const float* __restrict__ b3,
    const int* __restrict__ off, const int* __restrict__ ssrc,
    float* __restrict__ out, int n) {
    const int wid = blockIdx.x * 4 + (threadIdx.x >> 6);
    const int lane = threadIdx.x & 63;
    if (wid >= n) return;
    const float xrv = xr3[wid];
    const float att = att3[0];
    float num = 0.f, den = 0.f;
    const int s0 = off[wid], s1 = off[wid + 1];
    for (int e = s0 - 1 + lane; e < s1; e += 64) {
        int src = (e < s0) ? wid : ssrc[e];
        float xlv = xl3[src];
        float t = xlv + xrv;
        float g = t > 0.f ? t : 0.2f * t;
        float ex = expf(g * att);
        den += ex;
        num += ex * xlv;
    }
    num = wave_reduce_sum(num);
    den = wave_reduce_sum(den);
    if (lane == 0) out[wid] = num / (den + 1e-16f) + b3[0];
}

// ---------------------------------------------------------------------------
// Link-prediction loss on bf16 z [N,128] (3.49 MB -> fits per-XCD L2).
// ---------------------------------------------------------------------------
__global__ __launch_bounds__(256) void loss_kernel(
    const __hip_bfloat16* __restrict__ zb, const int* __restrict__ pos,
    const int* __restrict__ neg, float* __restrict__ lsum, int E) {
    const int lane = threadIdx.x & 63;
    const int sl = lane & 15;
    const int wlocal = threadIdx.x >> 6;
    const int q = lane >> 4;
    const int nq = gridDim.x * 16;
    const int qid = (blockIdx.x * 4 + wlocal) * 4 + q;
    const int total = 2 * E;
    float psum = 0.f, nsum = 0.f;

    for (int base = qid; base < total; base += 2 * nq) {
        uint4 au[2], bu[2];
        bool act[2], isN[2];
#pragma unroll
        for (int s = 0; s < 2; s++) {
            int it = base + s * nq;
            act[s] = it < total;
            int itc = act[s] ? it : 0;
            isN[s] = itc >= E;
            int e = isN[s] ? itc - E : itc;
            const int* ei = isN[s] ? neg : pos;
            int u = ei[e], v = ei[E + e];
            au[s] = *(const uint4*)(zb + (size_t)u * 128 + sl * 8);
            bu[s] = *(const uint4*)(zb + (size_t)v * 128 + sl * 8);
        }
#pragma unroll
        for (int s = 0; s < 2; s++) {
            float p = blo(au[s].x) * blo(bu[s].x) + bhi(au[s].x) * bhi(bu[s].x)
                    + blo(au[s].y) * blo(bu[s].y) + bhi(au[s].y) * bhi(bu[s].y)
                    + blo(au[s].z) * blo(bu[s].z) + bhi(au[s].z) * bhi(bu[s].z)
                    + blo(au[s].w) * blo(bu[s].w) + bhi(au[s].w) * bhi(bu[s].w);
            p += __shfl_xor(p, 1, 64);
            p += __shfl_xor(p, 2, 64);
            p += __shfl_xor(p, 4, 64);
            p += __shfl_xor(p, 8, 64);
            if (sl == 0 && act[s]) {
                float sig = 1.f / (1.f + expf(-p));
                if (isN[s]) nsum += logf(1.f - sig + 1e-15f);
                else        psum += logf(sig + 1e-15f);
            }
        }
    }
    float pw = wave_reduce_sum(psum);
    float nw = wave_reduce_sum(nsum);
    __shared__ float sp[4], sn[4];
    if (lane == 0) { sp[wlocal] = pw; sn[wlocal] = nw; }
    __syncthreads();
    if (threadIdx.x == 0) {
        atomicAdd(&lsum[0], sp[0] + sp[1] + sp[2] + sp[3]);
        atomicAdd(&lsum[1], sn[0] + sn[1] + sn[2] + sn[3]);
    }
}

__global__ void finalize_kernel(const float* __restrict__ lsum,
                                const float* __restrict__ c1,
                                const float* __restrict__ c2,
                                float* __restrict__ out, int n, int E) {
    out[n]     = -(lsum[0] + lsum[1]) / (float)E;
    out[n + 1] = c1[0];
    out[n + 2] = c2[0];
}

// ---------------------------------------------------------------------------
extern "C" void kernel_launch(void* const* d_in, const int* in_sizes, int n_in,
                              void* d_out, int out_size, void* d_ws, size_t ws_size,
                              hipStream_t stream) {
    const float* x      = (const float*)d_in[0];
    const int*   ei     = (const int*)d_in[1];
    const int*   nei    = (const int*)d_in[2];
    const float* Wl1    = (const float*)d_in[3];
    const float* Wr1    = (const float*)d_in[4];
    const float* att1   = (const float*)d_in[5];
    const float* b1     = (const float*)d_in[6];
    const float* Wl2    = (const float*)d_in[7];
    const float* Wr2    = (const float*)d_in[8];
    const float* att2   = (const float*)d_in[9];
    const float* b2     = (const float*)d_in[10];
    const float* Wl3    = (const float*)d_in[11];
    const float* Wr3    = (const float*)d_in[12];
    const float* att3   = (const float*)d_in[13];
    const float* b3     = (const float*)d_in[14];
    const float* Wlin1  = (const float*)d_in[15];
    const float* blin1  = (const float*)d_in[16];
    const float* Wlin2  = (const float*)d_in[17];
    const float* blin2  = (const float*)d_in[18];
    const float* c1     = (const float*)d_in[19];
    const float* c2     = (const float*)d_in[20];
    float* out = (float*)d_out;

    const int E = in_sizes[1] / 2;   // 504378
    const int N = NODES;

    // ---- workspace carve (bytes), ~48.9 MB ----
    char* ws = (char*)d_ws;
    __hip_bfloat16* C1b = (__hip_bfloat16*)(ws + 0);
    __hip_bfloat16* C2b = (__hip_bfloat16*)(ws + 0);
    float*          xo  = (float*)(ws + 7000064);
    __hip_bfloat16* zb  = (__hip_bfloat16*)(ws + 12451072);
    __hip_bfloat16* xb  = (__hip_bfloat16*)(ws + 17442560);   // [N,512] bf16
    __hip_bfloat16* h1b = (__hip_bfloat16*)(ws + 31396608);   // [N,320] bf16
    float*          h2  = (float*)(ws + 40117888);            // [N,100] f32
    __hip_bfloat16* W1T = (__hip_bfloat16*)(ws + 45568688);   // [640,512]
    __hip_bfloat16* W2T = (__hip_bfloat16*)(ws + 46224048);   // [256,320]
    __hip_bfloat16* WsT = (__hip_bfloat16*)(ws + 46387888);   // [256,512]
    float*          bcat = (float*)(ws + 46650032);           // [256]
    float*          xl3 = (float*)(ws + 46651056);
    float*          xr3 = (float*)(ws + 46705564);
    int*            ioff = (int*)(ws + 46760072);             // N+1
    int*            cur  = (int*)(ws + 46814584);             // N
    int*            ssrc = (int*)(ws + 46869092);             // E
    float*          lsum = (float*)(ws + 48886604);           // 2

    hipMemsetAsync(cur, 0, sizeof(int) * N, stream);
    hipMemsetAsync(lsum, 0, sizeof(float) * 2, stream);

    // ---- CSR build ----
    hist_kernel<<<(E + 255) / 256, 256, 0, stream>>>(ei + E, cur, E);
    scan_kernel<<<1, 1024, 0, stream>>>(cur, ioff, N);
    scatter_kernel<<<(E + 255) / 256, 256, 0, stream>>>(ei, ei + E, cur, ssrc, E);

    // ---- pack inputs/weights (one fused launch) ----
    convert_all_kernel<<<(540928 + N * 128 + 255) / 256, 256, 0, stream>>>(
        x, Wl1, Wr1, Wl2, Wr2, Wlin1, Wlin2, blin1, blin2,
        W1T, W2T, WsT, bcat, xb, N);

    // ---- layer 1 ----
    mfma_gemm<__hip_bfloat16, false><<<dim3(10, 107), 256, 0, stream>>>(
        xb, W1T, C1b, nullptr, nullptr, nullptr, N, 512, 640, 640);
    gat_node_kernel<300, 5, 640, 320, __hip_bfloat16, __hip_bfloat16, true>
        <<<(N + 1) / 2, 256, 0, stream>>>(C1b, C1b + 300, att1, b1, ioff, ssrc, h1b, N);

    // ---- layer 2 ----
    mfma_gemm<__hip_bfloat16, false><<<dim3(4, 107), 256, 0, stream>>>(
        h1b, W2T, C2b, nullptr, nullptr, nullptr, N, 320, 256, 256);
    gat_node_kernel<100, 2, 256, 100, __hip_bfloat16, float, true>
        <<<(N + 1) / 2, 256, 0, stream>>>(C2b, C2b + 100, att2, b2, ioff, ssrc, h2, N);

    // ---- skip connections: xo f32 [N,100], zb bf16 [N,128] ----
    mfma_gemm<float, true><<<dim3(4, 107), 256, 0, stream>>>(
        xb, WsT, xo, bcat, h2, zb, N, 512, 256, 0);

    // ---- reconstruction loss ----
    loss_kernel<<<2048, 256, 0, stream>>>(zb, ei, nei, lsum, E);

    // ---- layer 3 ----
    gemm_vec1_kernel<<<(N + 3) / 4, 256, 0, stream>>>(xo, Wl3, Wr3, xl3, xr3, N, 100);
    gat3_kernel<<<(N + 3) / 4, 256, 0, stream>>>(xl3, xr3, att3, b3, ioff, ssrc, out, N);

    finalize_kernel<<<1, 1, 0, stream>>>(lsum, c1, c2, out, N, E);
}

// Round 6
// 441.831 us; speedup vs baseline: 2.2665x; 1.0816x over previous
//
#include <hip/hip_runtime.h>
#include <hip/hip_bf16.h>

#define NODES 13627
#define DIM   500

typedef short short8 __attribute__((ext_vector_type(8)));
typedef float f32x4 __attribute__((ext_vector_type(4)));

__device__ inline float wave_reduce_sum(float v) {
#pragma unroll
    for (int o = 32; o > 0; o >>= 1) v += __shfl_xor(v, o, 64);
    return v;
}

__device__ inline void store_v(float* p, float v) { *p = v; }
__device__ inline void store_v(__hip_bfloat16* p, float v) { *p = __float2bfloat16(v); }

// bf16 (packed pair in uint) -> f32, exact
__device__ inline float blo(unsigned w) { unsigned t = w << 16;        return __builtin_bit_cast(float, t); }
__device__ inline float bhi(unsigned w) { unsigned t = w & 0xffff0000u; return __builtin_bit_cast(float, t); }

struct b4 { __hip_bfloat16 a, b, c, d; };

__device__ inline void store4(__hip_bfloat16* p, float v0, float v1, float v2, float v3) {
    b4 o{__float2bfloat16(v0), __float2bfloat16(v1), __float2bfloat16(v2), __float2bfloat16(v3)};
    *(b4*)p = o;
}
__device__ inline void store4(float* p, float v0, float v1, float v2, float v3) {
    *(float4*)p = make_float4(v0, v1, v2, v3);
}

// ---------------------------------------------------------------------------
// CSR build: histogram -> scan -> scatter
// ---------------------------------------------------------------------------
__global__ __launch_bounds__(256) void hist_kernel(const int* __restrict__ dst,
                                                   int* __restrict__ cnt, int E) {
    int i = blockIdx.x * blockDim.x + threadIdx.x;
    if (i < E) atomicAdd(&cnt[dst[i]], 1);
}

__global__ __launch_bounds__(1024) void scan_kernel(int* __restrict__ cnt_cur,
                                                    int* __restrict__ off, int n) {
    __shared__ int wsum[16];
    const int tid = threadIdx.x, lane = tid & 63, w = tid >> 6;
    int carry = 0;
    for (int base = 0; base < n; base += 1024) {
        int i = base + tid;
        int v = (i < n) ? cnt_cur[i] : 0;
        int s = v;
#pragma unroll
        for (int o = 1; o < 64; o <<= 1) {
            int t = __shfl_up(s, o, 64);
            if (lane >= o) s += t;
        }
        if (lane == 63) wsum[w] = s;
        __syncthreads();
        if (w == 0 && lane < 16) {
            int x = wsum[lane];
            int sx = x;
#pragma unroll
            for (int o = 1; o < 16; o <<= 1) {
                int t = __shfl_up(sx, o, 64);
                if (lane >= o) sx += t;
            }
            wsum[lane] = sx;
        }
        __syncthreads();
        int wo = (w == 0) ? 0 : wsum[w - 1];
        int total = wsum[15];
        int excl = carry + wo + (s - v);
        if (i < n) { off[i] = excl; cnt_cur[i] = excl; }
        carry += total;
        __syncthreads();
    }
    if (tid == 0) off[n] = carry;
}

__global__ __launch_bounds__(256) void scatter_kernel(const int* __restrict__ src,
                                                      const int* __restrict__ dst,
                                                      int* __restrict__ cur,
                                                      int* __restrict__ ssrc, int E) {
    int i = blockIdx.x * blockDim.x + threadIdx.x;
    if (i < E) {
        int p = atomicAdd(&cur[dst[i]], 1);
        ssrc[p] = src[i];
    }
}

// ---------------------------------------------------------------------------
// Fused conversion / packing (weights + bias + x) in ONE launch.
// ---------------------------------------------------------------------------
__global__ __launch_bounds__(256) void convert_all_kernel(
    const float* __restrict__ x,
    const float* __restrict__ Wl1, const float* __restrict__ Wr1,
    const float* __restrict__ Wl2, const float* __restrict__ Wr2,
    const float* __restrict__ Ws1, const float* __restrict__ Ws2,
    const float* __restrict__ bs1, const float* __restrict__ bs2,
    __hip_bfloat16* __restrict__ W1T, __hip_bfloat16* __restrict__ W2T,
    __hip_bfloat16* __restrict__ WsT, float* __restrict__ bcat,
    __hip_bfloat16* __restrict__ xb, int M) {
    int i = blockIdx.x * 256 + threadIdx.x;
    if (i < 327680) {
        int n = i >> 9, k = i & 511;
        float v = 0.f;
        if (k < 500) {
            if (n < 300) v = Wl1[k * 300 + n];
            else if (n < 600) v = Wr1[k * 300 + n - 300];
        }
        W1T[i] = __float2bfloat16(v);
    } else if (i < 409600) {
        int j = i - 327680;
        int n = j / 320, k = j - n * 320;
        float v = 0.f;
        if (k < 300) {
            if (n < 100) v = Wl2[k * 100 + n];
            else if (n < 200) v = Wr2[k * 100 + n - 100];
        }
        W2T[j] = __float2bfloat16(v);
    } else if (i < 540672) {
        int j = i - 409600;
        int n = j >> 9, k = j & 511;
        float v = 0.f;
        if (k < 500) {
            if (n < 100) v = Ws1[k * 100 + n];
            else if (n < 200) v = Ws2[k * 100 + n - 100];
        }
        WsT[j] = __float2bfloat16(v);
    } else if (i < 540928) {
        int n = i - 540672;
        float v = 0.f;
        if (n < 100) v = bs1[n];
        else if (n < 200) v = bs2[n - 100];
        bcat[n] = v;
    } else {
        int j = i - 540928;
        if (j >= M * 128) return;
        int m = j >> 7, k = (j & 127) << 2;
        b4 o;
        if (k < 500) {
            float4 v = *(const float4*)(x + (size_t)m * 500 + k);
            o.a = __float2bfloat16(v.x); o.b = __float2bfloat16(v.y);
            o.c = __float2bfloat16(v.z); o.d = __float2bfloat16(v.w);
        } else {
            o.a = o.b = o.c = o.d = __float2bfloat16(0.f);
        }
        *(b4*)(xb + (size_t)m * 512 + k) = o;
    }
}

// ---------------------------------------------------------------------------
// bf16 MFMA GEMM: C[M,Nn] = A[M,Kp] @ BT[Nn,Kp]^T   (BM=128, BN=64, BK=32)
// ---------------------------------------------------------------------------
template <typename TC, bool SKIP>
__global__ __launch_bounds__(256) void mfma_gemm(
    const __hip_bfloat16* __restrict__ A, const __hip_bfloat16* __restrict__ BT,
    TC* __restrict__ C, const float* __restrict__ bias, const float* __restrict__ h2,
    __hip_bfloat16* __restrict__ zb, int M, int Kp, int Nn, int ldc) {
    __shared__ short AsF[8 * 64 * 8];
    __shared__ short BsF[4 * 64 * 8];
    const int t = threadIdx.x;
    const int w = t >> 6, lane = t & 63;
    const int c = t & 3, rr = t >> 2;
    const int m0 = blockIdx.y * 128, n0 = blockIdx.x * 64;

    f32x4 acc[2][4];
#pragma unroll
    for (int i = 0; i < 2; i++)
#pragma unroll
        for (int j = 0; j < 4; j++) acc[i][j] = (f32x4){0.f, 0.f, 0.f, 0.f};

    for (int k0 = 0; k0 < Kp; k0 += 32) {
#pragma unroll
        for (int r = 0; r < 2; r++) {
            int m = r * 64 + rr;
            int gm = m0 + m; if (gm >= M) gm = M - 1;
            float4 v = *(const float4*)(A + (size_t)gm * Kp + k0 + c * 8);
            int mi = m >> 4, sl = m & 15;
            *(float4*)(&AsF[(mi * 64 + c * 16 + sl) * 8]) = v;
        }
        {
            int n = rr;
            float4 v = *(const float4*)(BT + (size_t)(n0 + n) * Kp + k0 + c * 8);
            int ni = n >> 4, sl = n & 15;
            *(float4*)(&BsF[(ni * 64 + c * 16 + sl) * 8]) = v;
        }
        __syncthreads();
        short8 a0 = *(const short8*)(&AsF[((w * 2 + 0) * 64 + lane) * 8]);
        short8 a1 = *(const short8*)(&AsF[((w * 2 + 1) * 64 + lane) * 8]);
#pragma unroll
        for (int j = 0; j < 4; j++) {
            short8 b = *(const short8*)(&BsF[(j * 64 + lane) * 8]);
            acc[0][j] = __builtin_amdgcn_mfma_f32_16x16x32_bf16(a0, b, acc[0][j], 0, 0, 0);
            acc[1][j] = __builtin_amdgcn_mfma_f32_16x16x32_bf16(a1, b, acc[1][j], 0, 0, 0);
        }
        __syncthreads();
    }

    const int q = lane >> 4, sl = lane & 15;
#pragma unroll
    for (int i = 0; i < 2; i++) {
#pragma unroll
        for (int j = 0; j < 4; j++) {
#pragma unroll
            for (int reg = 0; reg < 4; reg++) {
                int gm = m0 + w * 32 + i * 16 + q * 4 + reg;
                int gn = n0 + j * 16 + sl;
                if (gm >= M) continue;
                float v = acc[i][j][reg];
                if constexpr (SKIP) {
                    if (gn < 200) {
                        int cn = gn < 100 ? gn : gn - 100;
                        float val = fmaxf(v + bias[gn], 0.f) + h2[(size_t)gm * 100 + cn];
                        if (gn < 100) C[(size_t)gm * 100 + gn] = val;
                        else zb[(size_t)gm * 128 + (gn - 100)] = __float2bfloat16(val);
                    } else if (gn < 228) {
                        zb[(size_t)gm * 128 + (gn - 100)] = __float2bfloat16(0.f);
                    }
                } else {
                    store_v(&C[(size_t)gm * ldc + gn], v);
                }
            }
        }
    }
}

// ---------------------------------------------------------------------------
// GATv2 edge+aggregate, quad-parallel: each wave processes 4 edges at once
// (one per 16-lane quad; lane covers f = sl*4 + j*64 + c). Two waves per
// node (edge range split, LDS combine — exact for this no-max softmax).
// Block = 256 = 4 waves = 2 nodes.
// ---------------------------------------------------------------------------
template <int F, int NJ, int SIN, int SOUT, typename TOUT, bool RELU>
__global__ __launch_bounds__(256) void gat_node_kernel(
    const __hip_bfloat16* __restrict__ xl, const __hip_bfloat16* __restrict__ xr,
    const float* __restrict__ att, const float* __restrict__ bias,
    const int* __restrict__ off, const int* __restrict__ ssrc,
    TOUT* __restrict__ out, int n) {
    __shared__ float sden[2];
    __shared__ float sacc[2][NJ * 64];
    const int t = threadIdx.x;
    const int lane = t & 63;
    const int sl = lane & 15, q = lane >> 4;
    const int half = (t >> 6) & 1;
    const int pairIdx = t >> 7;
    int wid = blockIdx.x * 2 + pairIdx;
    if (wid >= n) wid = n - 1;          // clamp; duplicate writes identical

    float attv[NJ * 4], xrv[NJ * 4], acc[NJ * 4];
    const __hip_bfloat16* xrrow = xr + (size_t)wid * SIN;
#pragma unroll
    for (int j = 0; j < NJ; j++) {
        const int f0 = sl * 4 + j * 64;
        if (f0 < F) {
            float4 a4 = *(const float4*)(att + f0);
            attv[j * 4 + 0] = a4.x; attv[j * 4 + 1] = a4.y;
            attv[j * 4 + 2] = a4.z; attv[j * 4 + 3] = a4.w;
        } else {
            attv[j * 4 + 0] = attv[j * 4 + 1] = attv[j * 4 + 2] = attv[j * 4 + 3] = 0.f;
        }
        uint2 u = *(const uint2*)(xrrow + f0);   // garbage beyond F is harmless (attv=0)
        xrv[j * 4 + 0] = blo(u.x); xrv[j * 4 + 1] = bhi(u.x);
        xrv[j * 4 + 2] = blo(u.y); xrv[j * 4 + 3] = bhi(u.y);
        acc[j * 4 + 0] = acc[j * 4 + 1] = acc[j * 4 + 2] = acc[j * 4 + 3] = 0.f;
    }

    const int s0 = off[wid], s1 = off[wid + 1];
    const int h0 = (s1 - s0) >> 1;      // wave0: self + h0 edges; wave1: rest
    const int eb = half ? (s0 + h0) : (s0 - 1);
    const int ee = half ? s1 : (s0 + h0);
    float den = 0.f;

    for (int e0 = eb; e0 < ee; e0 += 4) {
        const int eq = e0 + q;
        const bool act = eq < ee;
        int src = wid;
        if (act && eq >= s0) src = ssrc[eq];
        const __hip_bfloat16* xrow = xl + (size_t)src * SIN;
        float xlv[NJ * 4];
        float p = 0.f;
#pragma unroll
        for (int j = 0; j < NJ; j++) {
            uint2 u = *(const uint2*)(xrow + sl * 4 + j * 64);
            float v0 = blo(u.x), v1 = bhi(u.x), v2 = blo(u.y), v3 = bhi(u.y);
            xlv[j * 4 + 0] = v0; xlv[j * 4 + 1] = v1;
            xlv[j * 4 + 2] = v2; xlv[j * 4 + 3] = v3;
            float t0 = v0 + xrv[j * 4 + 0];
            float t1 = v1 + xrv[j * 4 + 1];
            float t2 = v2 + xrv[j * 4 + 2];
            float t3 = v3 + xrv[j * 4 + 3];
            p += attv[j * 4 + 0] * fmaxf(t0, 0.2f * t0);
            p += attv[j * 4 + 1] * fmaxf(t1, 0.2f * t1);
            p += attv[j * 4 + 2] * fmaxf(t2, 0.2f * t2);
            p += attv[j * 4 + 3] * fmaxf(t3, 0.2f * t3);
        }
        p += __shfl_xor(p, 1, 64);
        p += __shfl_xor(p, 2, 64);
        p += __shfl_xor(p, 4, 64);
        p += __shfl_xor(p, 8, 64);
        float ex = act ? expf(p) : 0.f;
        den += ex;
#pragma unroll
        for (int i = 0; i < NJ * 4; i++) acc[i] += ex * xlv[i];
    }

    // cross-quad butterfly (all lanes end with totals for this wave's range)
#pragma unroll
    for (int o = 16; o <= 32; o <<= 1) {
        den += __shfl_xor(den, o, 64);
#pragma unroll
        for (int i = 0; i < NJ * 4; i++) acc[i] += __shfl_xor(acc[i], o, 64);
    }

    if (half == 1 && lane < 16) {
        if (lane == 0) sden[pairIdx] = den;
#pragma unroll
        for (int j = 0; j < NJ; j++)
            *(float4*)(&sacc[pairIdx][sl * 4 + j * 64]) =
                make_float4(acc[j * 4 + 0], acc[j * 4 + 1], acc[j * 4 + 2], acc[j * 4 + 3]);
    }
    __syncthreads();
    if (half == 0 && lane < 16) {
        den += sden[pairIdx];
        const float inv = 1.f / (den + 1e-16f);
#pragma unroll
        for (int j = 0; j < NJ; j++) {
            const int f0 = sl * 4 + j * 64;
            if (f0 >= SOUT) continue;
            float4 o4 = *(float4*)(&sacc[pairIdx][f0]);
            float vv[4] = {acc[j * 4 + 0] + o4.x, acc[j * 4 + 1] + o4.y,
                           acc[j * 4 + 2] + o4.z, acc[j * 4 + 3] + o4.w};
            float r[4];
#pragma unroll
            for (int cc = 0; cc < 4; cc++) {
                const int f = f0 + cc;
                float v = 0.f;
                if (f < F) {
                    v = vv[cc] * inv + bias[f];
                    if (RELU) v = fmaxf(v, 0.f);
                }
                r[cc] = v;
            }
            store4(&out[(size_t)wid * SOUT + f0], r[0], r[1], r[2], r[3]);
        }
    }
}

// ---------------------------------------------------------------------------
// Layer-3 projections: xl3 = xo @ Wl3, xr3 = xo @ Wr3   (K=100)
// ---------------------------------------------------------------------------
__global__ __launch_bounds__(256) void gemm_vec1_kernel(
    const float* __restrict__ xo, const float* __restrict__ wl,
    const float* __restrict__ wr, float* __restrict__ xl3,
    float* __restrict__ xr3, int M, int ldx) {
    const int wid = blockIdx.x * 4 + (threadIdx.x >> 6);
    const int lane = threadIdx.x & 63;
    if (wid >= M) return;
    float a = 0.f, b = 0.f;
    for (int f = lane; f < 100; f += 64) {
        float v = xo[(size_t)wid * ldx + f];
        a += v * wl[f];
        b += v * wr[f];
    }
    a = wave_reduce_sum(a);
    b = wave_reduce_sum(b);
    if (lane == 0) { xl3[wid] = a; xr3[wid] = b; }
}

// ---------------------------------------------------------------------------
// Layer-3 GAT (F=1): wave per node, lanes parallel over edges.
// ---------------------------------------------------------------------------
__global__ __launch_bounds__(256) void gat3_kernel(
    const float* __restrict__ xl3, const float* __restrict__ xr3,
    const float* __restrict__ att3, const float* __restrict__ b3,
    const int* __restrict__ off, const int* __restrict__ ssrc,
    float* __restrict__ out, int n) {
    const int wid = blockIdx.x * 4 + (threadIdx.x >> 6);
    const int lane = threadIdx.x & 63;
    if (wid >= n) return;
    const float xrv = xr3[wid];
    const float att = att3[0];
    float num = 0.f, den = 0.f;
    const int s0 = off[wid], s1 = off[wid + 1];
    for (int e = s0 - 1 + lane; e < s1; e += 64) {
        int src = (e < s0) ? wid : ssrc[e];
        float xlv = xl3[src];
        float t = xlv + xrv;
        float g = t > 0.f ? t : 0.2f * t;
        float ex = expf(g * att);
        den += ex;
        num += ex * xlv;
    }
    num = wave_reduce_sum(num);
    den = wave_reduce_sum(den);
    if (lane == 0) out[wid] = num / (den + 1e-16f) + b3[0];
}

// ---------------------------------------------------------------------------
// Link-prediction loss on bf16 z [N,128] (3.49 MB -> fits per-XCD L2).
// ---------------------------------------------------------------------------
__global__ __launch_bounds__(256) void loss_kernel(
    const __hip_bfloat16* __restrict__ zb, const int* __restrict__ pos,
    const int* __restrict__ neg, float* __restrict__ lsum, int E) {
    const int lane = threadIdx.x & 63;
    const int sl = lane & 15;
    const int wlocal = threadIdx.x >> 6;
    const int q = lane >> 4;
    const int nq = gridDim.x * 16;
    const int qid = (blockIdx.x * 4 + wlocal) * 4 + q;
    const int total = 2 * E;
    float psum = 0.f, nsum = 0.f;

    for (int base = qid; base < total; base += 2 * nq) {
        uint4 au[2], bu[2];
        bool act[2], isN[2];
#pragma unroll
        for (int s = 0; s < 2; s++) {
            int it = base + s * nq;
            act[s] = it < total;
            int itc = act[s] ? it : 0;
            isN[s] = itc >= E;
            int e = isN[s] ? itc - E : itc;
            const int* ei = isN[s] ? neg : pos;
            int u = ei[e], v = ei[E + e];
            au[s] = *(const uint4*)(zb + (size_t)u * 128 + sl * 8);
            bu[s] = *(const uint4*)(zb + (size_t)v * 128 + sl * 8);
        }
#pragma unroll
        for (int s = 0; s < 2; s++) {
            float p = blo(au[s].x) * blo(bu[s].x) + bhi(au[s].x) * bhi(bu[s].x)
                    + blo(au[s].y) * blo(bu[s].y) + bhi(au[s].y) * bhi(bu[s].y)
                    + blo(au[s].z) * blo(bu[s].z) + bhi(au[s].z) * bhi(bu[s].z)
                    + blo(au[s].w) * blo(bu[s].w) + bhi(au[s].w) * bhi(bu[s].w);
            p += __shfl_xor(p, 1, 64);
            p += __shfl_xor(p, 2, 64);
            p += __shfl_xor(p, 4, 64);
            p += __shfl_xor(p, 8, 64);
            if (sl == 0 && act[s]) {
                float sig = 1.f / (1.f + expf(-p));
                if (isN[s]) nsum += logf(1.f - sig + 1e-15f);
                else        psum += logf(sig + 1e-15f);
            }
        }
    }
    float pw = wave_reduce_sum(psum);
    float nw = wave_reduce_sum(nsum);
    __shared__ float sp[4], sn[4];
    if (lane == 0) { sp[wlocal] = pw; sn[wlocal] = nw; }
    __syncthreads();
    if (threadIdx.x == 0) {
        atomicAdd(&lsum[0], sp[0] + sp[1] + sp[2] + sp[3]);
        atomicAdd(&lsum[1], sn[0] + sn[1] + sn[2] + sn[3]);
    }
}

__global__ void finalize_kernel(const float* __restrict__ lsum,
                                const float* __restrict__ c1,
                                const float* __restrict__ c2,
                                float* __restrict__ out, int n, int E) {
    out[n]     = -(lsum[0] + lsum[1]) / (float)E;
    out[n + 1] = c1[0];
    out[n + 2] = c2[0];
}

// ---------------------------------------------------------------------------
extern "C" void kernel_launch(void* const* d_in, const int* in_sizes, int n_in,
                              void* d_out, int out_size, void* d_ws, size_t ws_size,
                              hipStream_t stream) {
    const float* x      = (const float*)d_in[0];
    const int*   ei     = (const int*)d_in[1];
    const int*   nei    = (const int*)d_in[2];
    const float* Wl1    = (const float*)d_in[3];
    const float* Wr1    = (const float*)d_in[4];
    const float* att1   = (const float*)d_in[5];
    const float* b1     = (const float*)d_in[6];
    const float* Wl2    = (const float*)d_in[7];
    const float* Wr2    = (const float*)d_in[8];
    const float* att2   = (const float*)d_in[9];
    const float* b2     = (const float*)d_in[10];
    const float* Wl3    = (const float*)d_in[11];
    const float* Wr3    = (const float*)d_in[12];
    const float* att3   = (const float*)d_in[13];
    const float* b3     = (const float*)d_in[14];
    const float* Wlin1  = (const float*)d_in[15];
    const float* blin1  = (const float*)d_in[16];
    const float* Wlin2  = (const float*)d_in[17];
    const float* blin2  = (const float*)d_in[18];
    const float* c1     = (const float*)d_in[19];
    const float* c2     = (const float*)d_in[20];
    float* out = (float*)d_out;

    const int E = in_sizes[1] / 2;   // 504378
    const int N = NODES;

    // ---- workspace carve (bytes), ~48.9 MB ----
    char* ws = (char*)d_ws;
    __hip_bfloat16* C1b = (__hip_bfloat16*)(ws + 0);
    __hip_bfloat16* C2b = (__hip_bfloat16*)(ws + 0);
    float*          xo  = (float*)(ws + 7000064);
    __hip_bfloat16* zb  = (__hip_bfloat16*)(ws + 12451072);
    __hip_bfloat16* xb  = (__hip_bfloat16*)(ws + 17442560);   // [N,512] bf16
    __hip_bfloat16* h1b = (__hip_bfloat16*)(ws + 31396608);   // [N,320] bf16
    float*          h2  = (float*)(ws + 40117888);            // [N,100] f32
    __hip_bfloat16* W1T = (__hip_bfloat16*)(ws + 45568688);   // [640,512]
    __hip_bfloat16* W2T = (__hip_bfloat16*)(ws + 46224048);   // [256,320]
    __hip_bfloat16* WsT = (__hip_bfloat16*)(ws + 46387888);   // [256,512]
    float*          bcat = (float*)(ws + 46650032);           // [256]
    float*          xl3 = (float*)(ws + 46651056);
    float*          xr3 = (float*)(ws + 46705564);
    int*            ioff = (int*)(ws + 46760072);             // N+1
    int*            cur  = (int*)(ws + 46814584);             // N
    int*            ssrc = (int*)(ws + 46869092);             // E
    float*          lsum = (float*)(ws + 48886604);           // 2

    hipMemsetAsync(cur, 0, sizeof(int) * N, stream);
    hipMemsetAsync(lsum, 0, sizeof(float) * 2, stream);

    // ---- CSR build ----
    hist_kernel<<<(E + 255) / 256, 256, 0, stream>>>(ei + E, cur, E);
    scan_kernel<<<1, 1024, 0, stream>>>(cur, ioff, N);
    scatter_kernel<<<(E + 255) / 256, 256, 0, stream>>>(ei, ei + E, cur, ssrc, E);

    // ---- pack inputs/weights (one fused launch) ----
    convert_all_kernel<<<(540928 + N * 128 + 255) / 256, 256, 0, stream>>>(
        x, Wl1, Wr1, Wl2, Wr2, Wlin1, Wlin2, blin1, blin2,
        W1T, W2T, WsT, bcat, xb, N);

    // ---- layer 1 ----
    mfma_gemm<__hip_bfloat16, false><<<dim3(10, 107), 256, 0, stream>>>(
        xb, W1T, C1b, nullptr, nullptr, nullptr, N, 512, 640, 640);
    gat_node_kernel<300, 5, 640, 320, __hip_bfloat16, true>
        <<<(N + 1) / 2, 256, 0, stream>>>(C1b, C1b + 300, att1, b1, ioff, ssrc, h1b, N);

    // ---- layer 2 ----
    mfma_gemm<__hip_bfloat16, false><<<dim3(4, 107), 256, 0, stream>>>(
        h1b, W2T, C2b, nullptr, nullptr, nullptr, N, 320, 256, 256);
    gat_node_kernel<100, 2, 256, 100, float, true>
        <<<(N + 1) / 2, 256, 0, stream>>>(C2b, C2b + 100, att2, b2, ioff, ssrc, h2, N);

    // ---- skip connections: xo f32 [N,100], zb bf16 [N,128] ----
    mfma_gemm<float, true><<<dim3(4, 107), 256, 0, stream>>>(
        xb, WsT, xo, bcat, h2, zb, N, 512, 256, 0);

    // ---- reconstruction loss ----
    loss_kernel<<<2048, 256, 0, stream>>>(zb, ei, nei, lsum, E);

    // ---- layer 3 ----
    gemm_vec1_kernel<<<(N + 3) / 4, 256, 0, stream>>>(xo, Wl3, Wr3, xl3, xr3, N, 100);
    gat3_kernel<<<(N + 3) / 4, 256, 0, stream>>>(xl3, xr3, att3, b3, ioff, ssrc, out, N);

    finalize_kernel<<<1, 1, 0, stream>>>(lsum, c1, c2, out, N, E);
}